// Round 1
// baseline (956.164 us; speedup 1.0000x reference)
//
#include <hip/hip_runtime.h>
#include <cstdint>
#include <cstddef>

typedef _Float16 h16;
typedef __attribute__((ext_vector_type(8))) _Float16 h16x8;
typedef __attribute__((ext_vector_type(4))) _Float16 h16x4;
typedef __attribute__((ext_vector_type(4))) float f32x4;

constexpr int B_ = 64, LD = 512, LQ = 128, DIM = 512, STEPS = 2;
constexpr int MD = B_ * LD;   // 32768 d-rows total
constexpr int MQ = B_ * LQ;   // 8192 q-rows total
constexpr int KST = LD + LQ;  // 640 stacked-neighbor K

// ---------------------------------------------------------------------------
// Generic C = A * B^T GEMM, f16 inputs, fp32 MFMA accum, templated epilogue.
// A: [M,K] row-major, Bt: [N,K] row-major. M%128==0, N%128==0, K%32==0.
// Block 256 thr = 4 waves; tile 128x128; each wave 64x64 (4x4 MFMA 16x16x32).
// blockIdx.z = batch (strideA/strideB elements per batch).
// MFMA 16x16x32 layouts (measured, m89/m91):
//   A-frag: m = lane&15, k = (lane>>4)*8 + j
//   B-frag: n = lane&15, k = (lane>>4)*8 + j   (B[k][n] = Bt[n][k])
//   C/D:    col = lane&15, row = (lane>>4)*4 + r
// ---------------------------------------------------------------------------
template <class Epi>
__global__ __launch_bounds__(256) void gemm_bt(const h16* __restrict__ A,
                                               const h16* __restrict__ Bt,
                                               int K, long strideA, long strideB,
                                               Epi epi) {
  const int b = blockIdx.z;
  A += (long)b * strideA;
  Bt += (long)b * strideB;

  __shared__ __align__(16) h16 lA[128 * 40];  // stride 40 (=32+8) breaks bank aliasing, keeps 16B align
  __shared__ __align__(16) h16 lB[128 * 40];

  const int tid = threadIdx.x;
  const int lane = tid & 63;
  const int wv = tid >> 6;
  const int wm = (wv >> 1) * 64, wn = (wv & 1) * 64;
  const int quad = lane >> 4, l16 = lane & 15;
  const long tileM = (long)blockIdx.x * 128, tileN = (long)blockIdx.y * 128;
  const int r0 = tid >> 2;         // staging row (0..63)
  const int c0 = (tid & 3) * 8;    // staging col (0,8,16,24)

  f32x4 acc[4][4] = {};

  const h16* gA0 = A + (tileM + r0) * (long)K + c0;
  const h16* gA1 = gA0 + 64 * (long)K;
  const h16* gB0 = Bt + (tileN + r0) * (long)K + c0;
  const h16* gB1 = gB0 + 64 * (long)K;

  for (int k0 = 0; k0 < K; k0 += 32) {
    __syncthreads();
    *(h16x8*)&lA[r0 * 40 + c0]        = *(const h16x8*)(gA0 + k0);
    *(h16x8*)&lA[(r0 + 64) * 40 + c0] = *(const h16x8*)(gA1 + k0);
    *(h16x8*)&lB[r0 * 40 + c0]        = *(const h16x8*)(gB0 + k0);
    *(h16x8*)&lB[(r0 + 64) * 40 + c0] = *(const h16x8*)(gB1 + k0);
    __syncthreads();

    h16x8 af[4], bfr[4];
#pragma unroll
    for (int t = 0; t < 4; t++) {
      af[t]  = *(const h16x8*)&lA[(wm + t * 16 + l16) * 40 + quad * 8];
      bfr[t] = *(const h16x8*)&lB[(wn + t * 16 + l16) * 40 + quad * 8];
    }
#pragma unroll
    for (int i = 0; i < 4; i++)
#pragma unroll
      for (int j = 0; j < 4; j++)
        acc[i][j] = __builtin_amdgcn_mfma_f32_16x16x32_f16(af[i], bfr[j], acc[i][j], 0, 0, 0);
  }

#pragma unroll
  for (int i = 0; i < 4; i++) {
#pragma unroll
    for (int j = 0; j < 4; j++) {
      const int gm0 = (int)tileM + wm + i * 16 + quad * 4;
      const int gn  = (int)tileN + wn + j * 16 + l16;
#pragma unroll
      for (int r = 0; r < 4; r++) epi(b, gm0 + r, gn, acc[i][j][r]);
    }
  }
}

// --- epilogues --------------------------------------------------------------
// Dense d-GEMM: A=dnode[32768,512], Bt=[W_self|W_dd|W_qd][1536,512].
// n<512  -> self_d (h16, +b_self)
// n<1024 -> stackDT[b][c=n-512][j=l]      = d_w*v   (dd info, transposed)
// else   -> stackQT[b][c=n-1024][j=128+l] = d_w*v   (qd info, transposed)
struct EpiDenseD {
  const float* b_self; const float* d_w;
  h16* self_d; h16* stackDT; h16* stackQT;
  __device__ void operator()(int, int gm, int gn, float v) const {
    const int b = gm >> 9, l = gm & 511;
    if (gn < 512)
      self_d[(size_t)gm * 512 + gn] = (h16)(v + b_self[gn]);
    else if (gn < 1024)
      stackDT[((size_t)b * 512 + (gn - 512)) * 640 + l] = (h16)(d_w[gm] * v);
    else
      stackQT[((size_t)b * 512 + (gn - 1024)) * 640 + 128 + l] = (h16)(d_w[gm] * v);
  }
};
// Dense q-GEMM: A=qnode[8192,512], Bt=[W_self|W_qq|W_dq][1536,512].
struct EpiDenseQ {
  const float* b_self; const float* q_w;
  h16* self_q; h16* stackQT; h16* stackDT;
  __device__ void operator()(int, int gm, int gn, float v) const {
    const int b = gm >> 7, l = gm & 127;
    if (gn < 512)
      self_q[(size_t)gm * 512 + gn] = (h16)(v + b_self[gn]);
    else if (gn < 1024)
      stackQT[((size_t)b * 512 + (gn - 512)) * 640 + l] = (h16)(q_w[gm] * v);
    else
      stackDT[((size_t)b * 512 + (gn - 1024)) * 640 + 512 + l] = (h16)(q_w[gm] * v);
  }
};
// Aggregation d: A=maskD[b][512,640], Bt=stackDT[b][512,640]; v = dd_msg+dq_msg.
struct EpiAggD {
  const h16* self_d; const float* inv_dnb; float* outd; h16* dnode;
  __device__ void operator()(int b, int gm, int gn, float v) const {
    const size_t row = (size_t)b * 512 + gm;
    float val = (float)self_d[row * 512 + gn] + v * inv_dnb[row];
    val = fmaxf(val, 0.f);
    outd[row * 512 + gn] = val;
    dnode[row * 512 + gn] = (h16)val;
  }
};
struct EpiAggQ {
  const h16* self_q; const float* inv_qnb; float* outq; h16* qnode;
  __device__ void operator()(int b, int gm, int gn, float v) const {
    const size_t row = (size_t)b * 128 + gm;
    float val = (float)self_q[row * 512 + gn] + v * inv_qnb[row];
    val = fmaxf(val, 0.f);
    outq[row * 512 + gn] = val;
    qnode[row * 512 + gn] = (h16)val;
  }
};

// --- small kernels ----------------------------------------------------------
__global__ __launch_bounds__(256) void k_convert(const float* __restrict__ dn,
                                                 const float* __restrict__ qn,
                                                 h16* __restrict__ dnb,
                                                 h16* __restrict__ qnb) {
  const size_t i4 = ((size_t)blockIdx.x * 256 + threadIdx.x) * 4;
  constexpr size_t TD = (size_t)MD * DIM;
  const float* src; h16* dst; size_t idx;
  if (i4 < TD) { src = dn; dst = dnb; idx = i4; }
  else         { src = qn; dst = qnb; idx = i4 - TD; }
  const float4 v = *(const float4*)&src[idx];
  h16x4 o; o.x = (h16)v.x; o.y = (h16)v.y; o.z = (h16)v.z; o.w = (h16)v.w;
  *(h16x4*)&dst[idx] = o;
}

__global__ __launch_bounds__(256) void k_wcat(const float* __restrict__ Wself,
                                              const float* __restrict__ Wdd,
                                              const float* __restrict__ Wqd,
                                              const float* __restrict__ Wqq,
                                              const float* __restrict__ Wdq,
                                              h16* __restrict__ catD,
                                              h16* __restrict__ catQ) {
  const int i = blockIdx.x * 256 + threadIdx.x;  // < 1536*512
  float vD, vQ;
  if (i < 512 * 512)            { vD = Wself[i];             vQ = vD; }
  else if (i < 1024 * 512)      { vD = Wdd[i - 512 * 512];   vQ = Wqq[i - 512 * 512]; }
  else                          { vD = Wqd[i - 1024 * 512];  vQ = Wdq[i - 1024 * 512]; }
  catD[i] = (h16)vD; catQ[i] = (h16)vQ;
}

// maskD[b][i][j]: j<512 -> dd[b][i][j], else dq[b][i][j-512]; row-sum -> 1/max(nb,1)
__global__ __launch_bounds__(256) void k_maskD(const int* __restrict__ dd,
                                               const int* __restrict__ dq,
                                               h16* __restrict__ maskD,
                                               float* __restrict__ inv_dnb) {
  const int row = blockIdx.x * 4 + (threadIdx.x >> 6);
  const int lane = threadIdx.x & 63;
  const int* pdd = dd + (size_t)row * 512;
  const int* pdq = dq + (size_t)row * 128;
  h16* pm = maskD + (size_t)row * 640;
  float s = 0.f;
  for (int j = lane; j < 640; j += 64) {
    const int v = (j < 512) ? pdd[j] : pdq[j - 512];
    s += (float)v;
    pm[j] = (h16)(float)v;
  }
  for (int m = 32; m; m >>= 1) s += __shfl_xor(s, m);
  if (lane == 0) inv_dnb[row] = 1.f / fmaxf(s, 1.f);
}

// maskQ[b][i][j]: j<128 -> qq[b][i][j], else qd[b][i][j-128]
__global__ __launch_bounds__(256) void k_maskQ(const int* __restrict__ qq,
                                               const int* __restrict__ qd,
                                               h16* __restrict__ maskQ,
                                               float* __restrict__ inv_qnb) {
  const int row = blockIdx.x * 4 + (threadIdx.x >> 6);
  const int lane = threadIdx.x & 63;
  const int* pqq = qq + (size_t)row * 128;
  const int* pqd = qd + (size_t)row * 512;
  h16* pm = maskQ + (size_t)row * 640;
  float s = 0.f;
  for (int j = lane; j < 640; j += 64) {
    const int v = (j < 128) ? pqq[j] : pqd[j - 128];
    s += (float)v;
    pm[j] = (h16)(float)v;
  }
  for (int m = 32; m; m >>= 1) s += __shfl_xor(s, m);
  if (lane == 0) inv_qnb[row] = 1.f / fmaxf(s, 1.f);
}

// sigmoid gate per node row: one wave per row (d rows then q rows)
__global__ __launch_bounds__(256) void k_w(const h16* __restrict__ dnb,
                                           const h16* __restrict__ qnb,
                                           const float* __restrict__ Wnw,
                                           const float* __restrict__ bnw,
                                           float* __restrict__ d_w,
                                           float* __restrict__ q_w,
                                           float* __restrict__ adw,
                                           float* __restrict__ aqw, int it) {
  const int row = blockIdx.x * 4 + (threadIdx.x >> 6);
  const int lane = threadIdx.x & 63;
  const bool isD = row < MD;
  const h16* node = isD ? dnb + (size_t)row * 512 : qnb + (size_t)(row - MD) * 512;
  const h16x8 v = *(const h16x8*)&node[lane * 8];
  float s = 0.f;
#pragma unroll
  for (int j = 0; j < 8; j++) s += (float)v[j] * Wnw[lane * 8 + j];
  for (int m = 32; m; m >>= 1) s += __shfl_xor(s, m);
  if (lane == 0) {
    const float w = 1.f / (1.f + expf(-(s + bnw[0])));
    if (isD) {
      d_w[row] = w;
      adw[((size_t)(row >> 9) * STEPS + it) * 512 + (row & 511)] = w;
    } else {
      const int rq = row - MD;
      q_w[rq] = w;
      aqw[((size_t)(rq >> 7) * STEPS + it) * 128 + (rq & 127)] = w;
    }
  }
}

// ---------------------------------------------------------------------------
extern "C" void kernel_launch(void* const* d_in, const int* in_sizes, int n_in,
                              void* d_out, int out_size, void* d_ws, size_t ws_size,
                              hipStream_t stream) {
  (void)in_sizes; (void)n_in; (void)out_size; (void)ws_size;

  const float* d_node = (const float*)d_in[0];
  const float* q_node = (const float*)d_in[1];
  const int*   qq     = (const int*)d_in[2];
  const int*   dq     = (const int*)d_in[3];
  const int*   dd     = (const int*)d_in[4];
  const int*   qd     = (const int*)d_in[5];
  const float* W_nw   = (const float*)d_in[6];
  const float* b_nw   = (const float*)d_in[7];
  const float* W_self = (const float*)d_in[8];
  const float* b_self = (const float*)d_in[9];
  const float* W_dd   = (const float*)d_in[10];
  const float* W_qq   = (const float*)d_in[11];
  const float* W_dq   = (const float*)d_in[12];
  const float* W_qd   = (const float*)d_in[13];

  float* outd = (float*)d_out;                         // [B,Ld,D]
  float* outq = outd + (size_t)MD * DIM;               // [B,Lq,D]
  float* adw  = outq + (size_t)MQ * DIM;               // [B,STEPS,Ld]
  float* aqw  = adw + (size_t)B_ * STEPS * LD;         // [B,STEPS,Lq]

  char* p = (char*)d_ws;
  auto alloc = [&](size_t bytes) { char* r = p; p += bytes; return r; };
  h16* dnode   = (h16*)alloc((size_t)MD * DIM * 2);      // 33.5 MB
  h16* qnode   = (h16*)alloc((size_t)MQ * DIM * 2);      //  8.4 MB
  h16* catD    = (h16*)alloc((size_t)1536 * 512 * 2);    //  1.6 MB
  h16* catQ    = (h16*)alloc((size_t)1536 * 512 * 2);    //  1.6 MB
  h16* maskD   = (h16*)alloc((size_t)B_ * LD * KST * 2); // 41.9 MB
  h16* maskQ   = (h16*)alloc((size_t)B_ * LQ * KST * 2); // 10.5 MB
  h16* stackDT = (h16*)alloc((size_t)B_ * 512 * KST * 2);// 41.9 MB
  h16* stackQT = (h16*)alloc((size_t)B_ * 512 * KST * 2);// 41.9 MB
  h16* self_d  = (h16*)alloc((size_t)MD * DIM * 2);      // 33.5 MB
  h16* self_q  = (h16*)alloc((size_t)MQ * DIM * 2);      //  8.4 MB
  float* d_wb    = (float*)alloc((size_t)MD * 4);
  float* q_wb    = (float*)alloc((size_t)MQ * 4);
  float* inv_dnb = (float*)alloc((size_t)MD * 4);
  float* inv_qnb = (float*)alloc((size_t)MQ * 4);

  // one-time prep
  k_convert<<<dim3((MD * DIM + MQ * DIM) / 4 / 256), 256, 0, stream>>>(d_node, q_node, dnode, qnode);
  k_wcat<<<dim3(1536 * 512 / 256), 256, 0, stream>>>(W_self, W_dd, W_qd, W_qq, W_dq, catD, catQ);
  k_maskD<<<dim3(MD / 4), 256, 0, stream>>>(dd, dq, maskD, inv_dnb);
  k_maskQ<<<dim3(MQ / 4), 256, 0, stream>>>(qq, qd, maskQ, inv_qnb);

  for (int it = 0; it < STEPS; it++) {
    k_w<<<dim3((MD + MQ) / 4), 256, 0, stream>>>(dnode, qnode, W_nw, b_nw, d_wb, q_wb, adw, aqw, it);
    gemm_bt<<<dim3(MD / 128, 1536 / 128, 1), 256, 0, stream>>>(
        dnode, catD, 512, 0L, 0L, EpiDenseD{b_self, d_wb, self_d, stackDT, stackQT});
    gemm_bt<<<dim3(MQ / 128, 1536 / 128, 1), 256, 0, stream>>>(
        qnode, catQ, 512, 0L, 0L, EpiDenseQ{b_self, q_wb, self_q, stackQT, stackDT});
    gemm_bt<<<dim3(LD / 128, 512 / 128, B_), 256, 0, stream>>>(
        maskD, stackDT, KST, (long)LD * KST, (long)512 * KST,
        EpiAggD{self_d, inv_dnb, outd, dnode});
    gemm_bt<<<dim3(LQ / 128, 512 / 128, B_), 256, 0, stream>>>(
        maskQ, stackQT, KST, (long)LQ * KST, (long)512 * KST,
        EpiAggQ{self_q, inv_qnb, outq, qnode});
  }
}

// Round 2
// 892.184 us; speedup vs baseline: 1.0717x; 1.0717x over previous
//
#include <hip/hip_runtime.h>
#include <cstdint>
#include <cstddef>

typedef _Float16 h16;
typedef __attribute__((ext_vector_type(8))) _Float16 h16x8;
typedef __attribute__((ext_vector_type(4))) _Float16 h16x4;
typedef __attribute__((ext_vector_type(4))) float f32x4;

constexpr int B_ = 64, LD = 512, LQ = 128, DIM = 512, STEPS = 2;
constexpr int MD = B_ * LD;   // 32768 d-rows total
constexpr int MQ = B_ * LQ;   // 8192 q-rows total
constexpr int KST = LD + LQ;  // 640 stacked-neighbor K

// async global->LDS, 16B per lane; LDS dest must be wave-uniform base + lane*16
#define ASYNC16(gp, lp)                                                          \
  __builtin_amdgcn_global_load_lds(                                              \
      (const __attribute__((address_space(1))) unsigned int*)(gp),               \
      (__attribute__((address_space(3))) unsigned int*)(lp), 16, 0, 0)

// ---------------------------------------------------------------------------
// Generic C = A * B^T GEMM, f16 inputs, fp32 MFMA accum, templated epilogue.
// A: [M,K] row-major, Bt: [N,K] row-major. M%128==0, N%128==0, K%32==0.
// Block 256 thr = 4 waves; tile 128x128; each wave 64x64 (4x4 MFMA 16x16x32).
// Staging via global_load_lds width=16 (m97 structure): LDS rows stride 32 h16
// (64 B), thread t stages row t>>2, cols (t&3)*8 -> LDS offset t*8 elements
// (wave-contiguous, as the DMA requires; NO padding allowed).
// MFMA 16x16x32 layouts (measured, m89/m91):
//   A-frag: m = lane&15, k = (lane>>4)*8 + j
//   B-frag: n = lane&15, k = (lane>>4)*8 + j   (B[k][n] = Bt[n][k])
//   C/D:    col = lane&15, row = (lane>>4)*4 + r
// ---------------------------------------------------------------------------
template <class Epi>
__global__ __launch_bounds__(256) void gemm_bt(const h16* __restrict__ A,
                                               const h16* __restrict__ Bt,
                                               int K, long strideA, long strideB,
                                               Epi epi) {
  const int b = blockIdx.z;
  A += (long)b * strideA;
  Bt += (long)b * strideB;

  __shared__ __align__(16) h16 lA[128 * 32];
  __shared__ __align__(16) h16 lB[128 * 32];

  const int tid = threadIdx.x;
  const int lane = tid & 63;
  const int wv = tid >> 6;
  const int wm = (wv >> 1) * 64, wn = (wv & 1) * 64;
  const int quad = lane >> 4, l16 = lane & 15;
  const long tileM = (long)blockIdx.x * 128, tileN = (long)blockIdx.y * 128;
  const int r0 = tid >> 2;         // staging row (0..63)
  const int c0 = (tid & 3) * 8;    // staging col (0,8,16,24)

  f32x4 acc[4][4] = {};

  const h16* gA0 = A + (tileM + r0) * (long)K + c0;
  const h16* gA1 = gA0 + 64 * (long)K;
  const h16* gB0 = Bt + (tileN + r0) * (long)K + c0;
  const h16* gB1 = gB0 + 64 * (long)K;
  h16* const dA0 = &lA[tid * 8];
  h16* const dA1 = &lA[tid * 8 + 64 * 32];
  h16* const dB0 = &lB[tid * 8];
  h16* const dB1 = &lB[tid * 8 + 64 * 32];

  for (int k0 = 0; k0 < K; k0 += 32) {
    __syncthreads();
    ASYNC16(gA0 + k0, dA0);
    ASYNC16(gA1 + k0, dA1);
    ASYNC16(gB0 + k0, dB0);
    ASYNC16(gB1 + k0, dB1);
    __syncthreads();

    h16x8 af[4], bfr[4];
#pragma unroll
    for (int t = 0; t < 4; t++) {
      af[t]  = *(const h16x8*)&lA[(wm + t * 16 + l16) * 32 + quad * 8];
      bfr[t] = *(const h16x8*)&lB[(wn + t * 16 + l16) * 32 + quad * 8];
    }
#pragma unroll
    for (int i = 0; i < 4; i++)
#pragma unroll
      for (int j = 0; j < 4; j++)
        acc[i][j] = __builtin_amdgcn_mfma_f32_16x16x32_f16(af[i], bfr[j], acc[i][j], 0, 0, 0);
  }

#pragma unroll
  for (int i = 0; i < 4; i++) {
#pragma unroll
    for (int j = 0; j < 4; j++) {
      const int gm0 = (int)tileM + wm + i * 16 + quad * 4;
      const int gn  = (int)tileN + wn + j * 16 + l16;
#pragma unroll
      for (int r = 0; r < 4; r++) epi(b, gm0 + r, gn, acc[i][j][r]);
    }
  }
}

// --- epilogues --------------------------------------------------------------
// Dense d-GEMM: A=dnode[32768,512], Bt=[W_self|W_dd|W_qd][1536,512].
// n<512  -> self_d (h16, +b_self)
// n<1024 -> stackDT[b][c=n-512][j=l]      = d_w*v   (dd info, transposed)
// else   -> stackQT[b][c=n-1024][j=128+l] = d_w*v   (qd info, transposed)
struct EpiDenseD {
  const float* b_self; const float* d_w;
  h16* self_d; h16* stackDT; h16* stackQT;
  __device__ void operator()(int, int gm, int gn, float v) const {
    const int b = gm >> 9, l = gm & 511;
    if (gn < 512)
      self_d[(size_t)gm * 512 + gn] = (h16)(v + b_self[gn]);
    else if (gn < 1024)
      stackDT[((size_t)b * 512 + (gn - 512)) * 640 + l] = (h16)(d_w[gm] * v);
    else
      stackQT[((size_t)b * 512 + (gn - 1024)) * 640 + 128 + l] = (h16)(d_w[gm] * v);
  }
};
// Dense q-GEMM: A=qnode[8192,512], Bt=[W_self|W_qq|W_dq][1536,512].
struct EpiDenseQ {
  const float* b_self; const float* q_w;
  h16* self_q; h16* stackQT; h16* stackDT;
  __device__ void operator()(int, int gm, int gn, float v) const {
    const int b = gm >> 7, l = gm & 127;
    if (gn < 512)
      self_q[(size_t)gm * 512 + gn] = (h16)(v + b_self[gn]);
    else if (gn < 1024)
      stackQT[((size_t)b * 512 + (gn - 512)) * 640 + l] = (h16)(q_w[gm] * v);
    else
      stackDT[((size_t)b * 512 + (gn - 1024)) * 640 + 512 + l] = (h16)(q_w[gm] * v);
  }
};
// Aggregation d: A=maskD[b][512,640], Bt=stackDT[b][512,640]; v = dd_msg+dq_msg.
// outd may be null (non-final iteration): skip the fp32 output write.
struct EpiAggD {
  const h16* self_d; const float* inv_dnb; float* outd; h16* dnode;
  __device__ void operator()(int b, int gm, int gn, float v) const {
    const size_t row = (size_t)b * 512 + gm;
    float val = (float)self_d[row * 512 + gn] + v * inv_dnb[row];
    val = fmaxf(val, 0.f);
    if (outd) outd[row * 512 + gn] = val;
    dnode[row * 512 + gn] = (h16)val;
  }
};
struct EpiAggQ {
  const h16* self_q; const float* inv_qnb; float* outq; h16* qnode;
  __device__ void operator()(int b, int gm, int gn, float v) const {
    const size_t row = (size_t)b * 128 + gm;
    float val = (float)self_q[row * 512 + gn] + v * inv_qnb[row];
    val = fmaxf(val, 0.f);
    if (outq) outq[row * 512 + gn] = val;
    qnode[row * 512 + gn] = (h16)val;
  }
};

// --- small kernels ----------------------------------------------------------
__global__ __launch_bounds__(256) void k_convert(const float* __restrict__ dn,
                                                 const float* __restrict__ qn,
                                                 h16* __restrict__ dnb,
                                                 h16* __restrict__ qnb) {
  const size_t i4 = ((size_t)blockIdx.x * 256 + threadIdx.x) * 4;
  constexpr size_t TD = (size_t)MD * DIM;
  const float* src; h16* dst; size_t idx;
  if (i4 < TD) { src = dn; dst = dnb; idx = i4; }
  else         { src = qn; dst = qnb; idx = i4 - TD; }
  const float4 v = *(const float4*)&src[idx];
  h16x4 o; o.x = (h16)v.x; o.y = (h16)v.y; o.z = (h16)v.z; o.w = (h16)v.w;
  *(h16x4*)&dst[idx] = o;
}

__global__ __launch_bounds__(256) void k_wcat(const float* __restrict__ Wself,
                                              const float* __restrict__ Wdd,
                                              const float* __restrict__ Wqd,
                                              const float* __restrict__ Wqq,
                                              const float* __restrict__ Wdq,
                                              h16* __restrict__ catD,
                                              h16* __restrict__ catQ) {
  const int i = blockIdx.x * 256 + threadIdx.x;  // < 1536*512
  float vD, vQ;
  if (i < 512 * 512)            { vD = Wself[i];             vQ = vD; }
  else if (i < 1024 * 512)      { vD = Wdd[i - 512 * 512];   vQ = Wqq[i - 512 * 512]; }
  else                          { vD = Wqd[i - 1024 * 512];  vQ = Wdq[i - 1024 * 512]; }
  catD[i] = (h16)vD; catQ[i] = (h16)vQ;
}

// maskD[b][i][j]: j<512 -> dd[b][i][j], else dq[b][i][j-512]; row-sum -> 1/max(nb,1)
__global__ __launch_bounds__(256) void k_maskD(const int* __restrict__ dd,
                                               const int* __restrict__ dq,
                                               h16* __restrict__ maskD,
                                               float* __restrict__ inv_dnb) {
  const int row = blockIdx.x * 4 + (threadIdx.x >> 6);
  const int lane = threadIdx.x & 63;
  const int* pdd = dd + (size_t)row * 512;
  const int* pdq = dq + (size_t)row * 128;
  h16* pm = maskD + (size_t)row * 640;
  float s = 0.f;
  for (int j = lane; j < 640; j += 64) {
    const int v = (j < 512) ? pdd[j] : pdq[j - 512];
    s += (float)v;
    pm[j] = (h16)(float)v;
  }
  for (int m = 32; m; m >>= 1) s += __shfl_xor(s, m);
  if (lane == 0) inv_dnb[row] = 1.f / fmaxf(s, 1.f);
}

// maskQ[b][i][j]: j<128 -> qq[b][i][j], else qd[b][i][j-128]
__global__ __launch_bounds__(256) void k_maskQ(const int* __restrict__ qq,
                                               const int* __restrict__ qd,
                                               h16* __restrict__ maskQ,
                                               float* __restrict__ inv_qnb) {
  const int row = blockIdx.x * 4 + (threadIdx.x >> 6);
  const int lane = threadIdx.x & 63;
  const int* pqq = qq + (size_t)row * 128;
  const int* pqd = qd + (size_t)row * 512;
  h16* pm = maskQ + (size_t)row * 640;
  float s = 0.f;
  for (int j = lane; j < 640; j += 64) {
    const int v = (j < 128) ? pqq[j] : pqd[j - 128];
    s += (float)v;
    pm[j] = (h16)(float)v;
  }
  for (int m = 32; m; m >>= 1) s += __shfl_xor(s, m);
  if (lane == 0) inv_qnb[row] = 1.f / fmaxf(s, 1.f);
}

// sigmoid gate per node row: one wave per row (d rows then q rows)
__global__ __launch_bounds__(256) void k_w(const h16* __restrict__ dnb,
                                           const h16* __restrict__ qnb,
                                           const float* __restrict__ Wnw,
                                           const float* __restrict__ bnw,
                                           float* __restrict__ d_w,
                                           float* __restrict__ q_w,
                                           float* __restrict__ adw,
                                           float* __restrict__ aqw, int it) {
  const int row = blockIdx.x * 4 + (threadIdx.x >> 6);
  const int lane = threadIdx.x & 63;
  const bool isD = row < MD;
  const h16* node = isD ? dnb + (size_t)row * 512 : qnb + (size_t)(row - MD) * 512;
  const h16x8 v = *(const h16x8*)&node[lane * 8];
  const float4 w0 = *(const float4*)&Wnw[lane * 8];
  const float4 w1 = *(const float4*)&Wnw[lane * 8 + 4];
  float s = (float)v[0] * w0.x + (float)v[1] * w0.y + (float)v[2] * w0.z +
            (float)v[3] * w0.w + (float)v[4] * w1.x + (float)v[5] * w1.y +
            (float)v[6] * w1.z + (float)v[7] * w1.w;
  for (int m = 32; m; m >>= 1) s += __shfl_xor(s, m);
  if (lane == 0) {
    const float w = 1.f / (1.f + expf(-(s + bnw[0])));
    if (isD) {
      d_w[row] = w;
      adw[((size_t)(row >> 9) * STEPS + it) * 512 + (row & 511)] = w;
    } else {
      const int rq = row - MD;
      q_w[rq] = w;
      aqw[((size_t)(rq >> 7) * STEPS + it) * 128 + (rq & 127)] = w;
    }
  }
}

// ---------------------------------------------------------------------------
extern "C" void kernel_launch(void* const* d_in, const int* in_sizes, int n_in,
                              void* d_out, int out_size, void* d_ws, size_t ws_size,
                              hipStream_t stream) {
  (void)in_sizes; (void)n_in; (void)out_size; (void)ws_size;

  const float* d_node = (const float*)d_in[0];
  const float* q_node = (const float*)d_in[1];
  const int*   qq     = (const int*)d_in[2];
  const int*   dq     = (const int*)d_in[3];
  const int*   dd     = (const int*)d_in[4];
  const int*   qd     = (const int*)d_in[5];
  const float* W_nw   = (const float*)d_in[6];
  const float* b_nw   = (const float*)d_in[7];
  const float* W_self = (const float*)d_in[8];
  const float* b_self = (const float*)d_in[9];
  const float* W_dd   = (const float*)d_in[10];
  const float* W_qq   = (const float*)d_in[11];
  const float* W_dq   = (const float*)d_in[12];
  const float* W_qd   = (const float*)d_in[13];

  float* outd = (float*)d_out;                         // [B,Ld,D]
  float* outq = outd + (size_t)MD * DIM;               // [B,Lq,D]
  float* adw  = outq + (size_t)MQ * DIM;               // [B,STEPS,Ld]
  float* aqw  = adw + (size_t)B_ * STEPS * LD;         // [B,STEPS,Lq]

  char* p = (char*)d_ws;
  auto alloc = [&](size_t bytes) { char* r = p; p += bytes; return r; };
  h16* dnode   = (h16*)alloc((size_t)MD * DIM * 2);      // 33.5 MB
  h16* qnode   = (h16*)alloc((size_t)MQ * DIM * 2);      //  8.4 MB
  h16* catD    = (h16*)alloc((size_t)1536 * 512 * 2);    //  1.6 MB
  h16* catQ    = (h16*)alloc((size_t)1536 * 512 * 2);    //  1.6 MB
  h16* maskD   = (h16*)alloc((size_t)B_ * LD * KST * 2); // 41.9 MB
  h16* maskQ   = (h16*)alloc((size_t)B_ * LQ * KST * 2); // 10.5 MB
  h16* stackDT = (h16*)alloc((size_t)B_ * 512 * KST * 2);// 41.9 MB
  h16* stackQT = (h16*)alloc((size_t)B_ * 512 * KST * 2);// 41.9 MB
  h16* self_d  = (h16*)alloc((size_t)MD * DIM * 2);      // 33.5 MB
  h16* self_q  = (h16*)alloc((size_t)MQ * DIM * 2);      //  8.4 MB
  float* d_wb    = (float*)alloc((size_t)MD * 4);
  float* q_wb    = (float*)alloc((size_t)MQ * 4);
  float* inv_dnb = (float*)alloc((size_t)MD * 4);
  float* inv_qnb = (float*)alloc((size_t)MQ * 4);

  // one-time prep
  k_convert<<<dim3((MD * DIM + MQ * DIM) / 4 / 256), 256, 0, stream>>>(d_node, q_node, dnode, qnode);
  k_wcat<<<dim3(1536 * 512 / 256), 256, 0, stream>>>(W_self, W_dd, W_qd, W_qq, W_dq, catD, catQ);
  k_maskD<<<dim3(MD / 4), 256, 0, stream>>>(dd, dq, maskD, inv_dnb);
  k_maskQ<<<dim3(MQ / 4), 256, 0, stream>>>(qq, qd, maskQ, inv_qnb);

  for (int it = 0; it < STEPS; it++) {
    const bool last = (it == STEPS - 1);
    k_w<<<dim3((MD + MQ) / 4), 256, 0, stream>>>(dnode, qnode, W_nw, b_nw, d_wb, q_wb, adw, aqw, it);
    gemm_bt<<<dim3(MD / 128, 1536 / 128, 1), 256, 0, stream>>>(
        dnode, catD, 512, 0L, 0L, EpiDenseD{b_self, d_wb, self_d, stackDT, stackQT});
    gemm_bt<<<dim3(MQ / 128, 1536 / 128, 1), 256, 0, stream>>>(
        qnode, catQ, 512, 0L, 0L, EpiDenseQ{b_self, q_wb, self_q, stackQT, stackDT});
    gemm_bt<<<dim3(LD / 128, 512 / 128, B_), 256, 0, stream>>>(
        maskD, stackDT, KST, (long)LD * KST, (long)512 * KST,
        EpiAggD{self_d, inv_dnb, last ? outd : nullptr, dnode});
    gemm_bt<<<dim3(LQ / 128, 512 / 128, B_), 256, 0, stream>>>(
        maskQ, stackQT, KST, (long)LQ * KST, (long)512 * KST,
        EpiAggQ{self_q, inv_qnb, last ? outq : nullptr, qnode});
  }
}

// Round 3
// 720.607 us; speedup vs baseline: 1.3269x; 1.2381x over previous
//
#include <hip/hip_runtime.h>
#include <cstdint>
#include <cstddef>

typedef _Float16 h16;
typedef __attribute__((ext_vector_type(8))) _Float16 h16x8;
typedef __attribute__((ext_vector_type(4))) _Float16 h16x4;
typedef __attribute__((ext_vector_type(4))) float f32x4;

constexpr int B_ = 64, LD = 512, LQ = 128, DIM = 512, STEPS = 2;
constexpr int MD = B_ * LD;   // 32768 d-rows total
constexpr int MQ = B_ * LQ;   // 8192 q-rows total
constexpr int KST = LD + LQ;  // 640 stacked-neighbor K
constexpr int KAGG = KST + DIM;  // 1152 = mask|node augmented K for agg GEMM

// A GEMM operand that switches source at k = ksplit (both K-contiguous).
struct Src {
  const h16* p0; int s0; long bstr0;  // rows for k in [0, ksplit)
  const h16* p1; int s1; long bstr1;  // rows for k in [ksplit, K)
  int ksplit;
};

// ---------------------------------------------------------------------------
// C = A * B^T, f16 in, fp32 MFMA accum. Block 256 = 4 waves, tile 128x128,
// wave 64x64 via 4x4 mfma_f32_16x16x32_f16. K%32==0; ksplit%32==0.
// LDS layout (per 128x32 tile): 16B chunk for (row, kq) lives at chunk index
//   p = 128*kq + (row ^ (2*kq)),  kq = k-quarter (8 h16 each).
// Staging: thread t loads rows t>>2 and 64+(t>>2), chunk kq=t&3 with
// global_load_dwordx4 (64B/4 lanes coalesced) and ds_write_b128 to p —
// conflict-free (per 8-lane phase, (row^2kq)&7 hits all 8 chunk groups).
// Fragment reads: lane l16 reads row wm+t*16+l16, chunk quad — also
// conflict-free under the same swizzle.
// MFMA 16x16x32 layouts (measured, m89/m91):
//   A-frag: m = lane&15, k = quad*8 + j ; B-frag: n = lane&15, k = quad*8+j
//   C/D:    col(n) = lane&15, row(m) = quad*4 + r
// ---------------------------------------------------------------------------
template <class Epi>
__global__ __launch_bounds__(256) void gemm2(Src sa, Src sb, int K, Epi epi) {
  const int b = blockIdx.z;

  __shared__ __align__(16) h16 lA[128 * 32];
  __shared__ __align__(16) h16 lB[128 * 32];

  const int tid = threadIdx.x;
  const int lane = tid & 63;
  const int wv = tid >> 6;
  const int wm = (wv >> 1) * 64, wn = (wv & 1) * 64;
  const int quad = lane >> 4, l16 = lane & 15;
  const long tileM = (long)blockIdx.x * 128, tileN = (long)blockIdx.y * 128;
  const int r = tid >> 2;        // staging row (0..63)
  const int kq = tid & 3;        // staging k-quarter

  // global staging pointers (lo = row r, hi = row r+64), per source
  const h16* pa0 = sa.p0 + (size_t)b * sa.bstr0 + (tileM + r) * (long)sa.s0 + kq * 8;
  const h16* pa0h = pa0 + 64L * sa.s0;
  const h16* pa1 = sa.p1 + (size_t)b * sa.bstr1 + (tileM + r) * (long)sa.s1 + kq * 8 - sa.ksplit;
  const h16* pa1h = pa1 + 64L * sa.s1;
  const h16* pb0 = sb.p0 + (size_t)b * sb.bstr0 + (tileN + r) * (long)sb.s0 + kq * 8;
  const h16* pb0h = pb0 + 64L * sb.s0;
  const h16* pb1 = sb.p1 + (size_t)b * sb.bstr1 + (tileN + r) * (long)sb.s1 + kq * 8 - sb.ksplit;
  const h16* pb1h = pb1 + 64L * sb.s1;

  // LDS staging destinations (swizzled chunk index); row+64 -> chunk+64
  const int pw = (kq * 128 + (r ^ (2 * kq))) * 8;
  h16* const dA = &lA[pw];
  h16* const dB = &lB[pw];

  // fragment LDS pointers (constant across K-loop)
  const h16* fA[4];
  const h16* fB[4];
#pragma unroll
  for (int t = 0; t < 4; t++) {
    const int rowA = wm + t * 16 + l16;
    const int rowB = wn + t * 16 + l16;
    fA[t] = &lA[(quad * 128 + (rowA ^ (2 * quad))) * 8];
    fB[t] = &lB[(quad * 128 + (rowB ^ (2 * quad))) * 8];
  }

  f32x4 acc[4][4] = {};

  for (int k0 = 0; k0 < K; k0 += 32) {
    const bool first = k0 < sa.ksplit;   // sa/sb share ksplit semantics per-operand
    const h16x8 va0 = *(const h16x8*)((first ? pa0 : pa1) + k0);
    const h16x8 va1 = *(const h16x8*)((first ? pa0h : pa1h) + k0);
    const bool firstB = k0 < sb.ksplit;
    const h16x8 vb0 = *(const h16x8*)((firstB ? pb0 : pb1) + k0);
    const h16x8 vb1 = *(const h16x8*)((firstB ? pb0h : pb1h) + k0);

    __syncthreads();
    *(h16x8*)dA = va0;
    *(h16x8*)(dA + 64 * 8) = va1;
    *(h16x8*)dB = vb0;
    *(h16x8*)(dB + 64 * 8) = vb1;
    __syncthreads();

    h16x8 af[4], bf[4];
#pragma unroll
    for (int t = 0; t < 4; t++) {
      af[t] = *(const h16x8*)fA[t];
      bf[t] = *(const h16x8*)fB[t];
    }
#pragma unroll
    for (int i = 0; i < 4; i++)
#pragma unroll
      for (int j = 0; j < 4; j++)
        acc[i][j] = __builtin_amdgcn_mfma_f32_16x16x32_f16(af[i], bf[j], acc[i][j], 0, 0, 0);
  }

#pragma unroll
  for (int i = 0; i < 4; i++) {
#pragma unroll
    for (int j = 0; j < 4; j++) {
      const int gm0 = (int)tileM + wm + i * 16 + quad * 4;
      const int gn  = (int)tileN + wn + j * 16 + l16;
#pragma unroll
      for (int rr = 0; rr < 4; rr++) epi(b, gm0 + rr, gn, acc[i][j][rr]);
    }
  }
}

// --- epilogues --------------------------------------------------------------
// Dense GEMM: A = [W_x|W_y] (1024 rows), Bt = node (all batches), C[o][node].
// Writes w[node]-scaled info into stack rows (lane-contiguous along node).
struct EpiDense {
  const float* w;   // gate per node (indexed by gn)
  h16* stackA;      // gm <  512 -> stackA[b][gm][offA + l]
  h16* stackB;      // gm >= 512 -> stackB[b][gm-512][offB + l]
  int lnShift;      // nodes-per-batch shift: 9 (d) or 7 (q)
  int offA, offB;
  __device__ void operator()(int, int gm, int gn, float v) const {
    const int b = gn >> lnShift, l = gn & ((1 << lnShift) - 1);
    const h16 sv = (h16)(w[gn] * v);
    if (gm < 512)
      stackA[((size_t)b * 512 + gm) * 640 + offA + l] = sv;
    else
      stackB[((size_t)b * 512 + (gm - 512)) * 640 + offB + l] = sv;
  }
};
// Agg GEMM: A = [mask'|node], Bt = [stackT|W_self], C[i][c] = self + msg/nb.
struct EpiAgg {
  const float* bias;  // b_self[c]
  float* out;         // fp32 final output or nullptr
  h16* nodeNext;      // next-iteration node buffer [i][c]
  int rowsPerB;       // 512 (d) or 128 (q)
  __device__ void operator()(int b, int gm, int gn, float v) const {
    const size_t row = (size_t)b * rowsPerB + gm;
    const float val = fmaxf(v + bias[gn], 0.f);
    if (out) out[row * 512 + gn] = val;
    nodeNext[row * 512 + gn] = (h16)val;
  }
};

// --- small kernels ----------------------------------------------------------
__global__ __launch_bounds__(256) void k_convert(const float* __restrict__ dn,
                                                 const float* __restrict__ qn,
                                                 h16* __restrict__ dnb,
                                                 h16* __restrict__ qnb) {
  const size_t i4 = ((size_t)blockIdx.x * 256 + threadIdx.x) * 4;
  constexpr size_t TD = (size_t)MD * DIM;
  const float* src; h16* dst; size_t idx;
  if (i4 < TD) { src = dn; dst = dnb; idx = i4; }
  else         { src = qn; dst = qnb; idx = i4 - TD; }
  const float4 v = *(const float4*)&src[idx];
  h16x4 o; o.x = (h16)v.x; o.y = (h16)v.y; o.z = (h16)v.z; o.w = (h16)v.w;
  *(h16x4*)&dst[idx] = o;
}

__global__ __launch_bounds__(256) void k_wcat(const float* __restrict__ Wself,
                                              const float* __restrict__ Wdd,
                                              const float* __restrict__ Wqd,
                                              const float* __restrict__ Wqq,
                                              const float* __restrict__ Wdq,
                                              h16* __restrict__ catD,
                                              h16* __restrict__ catQ) {
  const int i = blockIdx.x * 256 + threadIdx.x;  // < 1536*512
  float vD, vQ;
  if (i < 512 * 512)       { vD = Wself[i];            vQ = vD; }
  else if (i < 1024 * 512) { vD = Wdd[i - 512 * 512];  vQ = Wqq[i - 512 * 512]; }
  else                     { vD = Wqd[i - 1024 * 512]; vQ = Wdq[i - 1024 * 512]; }
  catD[i] = (h16)vD; catQ[i] = (h16)vQ;
}

// maskD'[b][i][j] = graph/nb : j<512 dd, else dq (premultiplied by 1/max(nb,1))
__global__ __launch_bounds__(256) void k_maskD(const int* __restrict__ dd,
                                               const int* __restrict__ dq,
                                               h16* __restrict__ maskD) {
  const int row = blockIdx.x * 4 + (threadIdx.x >> 6);
  const int lane = threadIdx.x & 63;
  const int* pdd = dd + (size_t)row * 512;
  const int* pdq = dq + (size_t)row * 128;
  h16* pm = maskD + (size_t)row * 640;
  float vals[10];
  float s = 0.f;
#pragma unroll
  for (int t = 0; t < 10; t++) {
    const int j = lane + t * 64;
    const float v = (float)((j < 512) ? pdd[j] : pdq[j - 512]);
    vals[t] = v; s += v;
  }
  for (int m = 32; m; m >>= 1) s += __shfl_xor(s, m);
  const float inv = 1.f / fmaxf(s, 1.f);
#pragma unroll
  for (int t = 0; t < 10; t++) pm[lane + t * 64] = (h16)(vals[t] * inv);
}

__global__ __launch_bounds__(256) void k_maskQ(const int* __restrict__ qq,
                                               const int* __restrict__ qd,
                                               h16* __restrict__ maskQ) {
  const int row = blockIdx.x * 4 + (threadIdx.x >> 6);
  const int lane = threadIdx.x & 63;
  const int* pqq = qq + (size_t)row * 128;
  const int* pqd = qd + (size_t)row * 512;
  h16* pm = maskQ + (size_t)row * 640;
  float vals[10];
  float s = 0.f;
#pragma unroll
  for (int t = 0; t < 10; t++) {
    const int j = lane + t * 64;
    const float v = (float)((j < 128) ? pqq[j] : pqd[j - 128]);
    vals[t] = v; s += v;
  }
  for (int m = 32; m; m >>= 1) s += __shfl_xor(s, m);
  const float inv = 1.f / fmaxf(s, 1.f);
#pragma unroll
  for (int t = 0; t < 10; t++) pm[lane + t * 64] = (h16)(vals[t] * inv);
}

// sigmoid gate per node row: one wave per row (d rows then q rows)
__global__ __launch_bounds__(256) void k_w(const h16* __restrict__ dnb,
                                           const h16* __restrict__ qnb,
                                           const float* __restrict__ Wnw,
                                           const float* __restrict__ bnw,
                                           float* __restrict__ d_w,
                                           float* __restrict__ q_w,
                                           float* __restrict__ adw,
                                           float* __restrict__ aqw, int it) {
  const int row = blockIdx.x * 4 + (threadIdx.x >> 6);
  const int lane = threadIdx.x & 63;
  const bool isD = row < MD;
  const h16* node = isD ? dnb + (size_t)row * 512 : qnb + (size_t)(row - MD) * 512;
  const h16x8 v = *(const h16x8*)&node[lane * 8];
  const float4 w0 = *(const float4*)&Wnw[lane * 8];
  const float4 w1 = *(const float4*)&Wnw[lane * 8 + 4];
  float s = (float)v[0] * w0.x + (float)v[1] * w0.y + (float)v[2] * w0.z +
            (float)v[3] * w0.w + (float)v[4] * w1.x + (float)v[5] * w1.y +
            (float)v[6] * w1.z + (float)v[7] * w1.w;
  for (int m = 32; m; m >>= 1) s += __shfl_xor(s, m);
  if (lane == 0) {
    const float w = 1.f / (1.f + expf(-(s + bnw[0])));
    if (isD) {
      d_w[row] = w;
      adw[((size_t)(row >> 9) * STEPS + it) * 512 + (row & 511)] = w;
    } else {
      const int rq = row - MD;
      q_w[rq] = w;
      aqw[((size_t)(rq >> 7) * STEPS + it) * 128 + (rq & 127)] = w;
    }
  }
}

// ---------------------------------------------------------------------------
extern "C" void kernel_launch(void* const* d_in, const int* in_sizes, int n_in,
                              void* d_out, int out_size, void* d_ws, size_t ws_size,
                              hipStream_t stream) {
  (void)in_sizes; (void)n_in; (void)out_size; (void)ws_size;

  const float* d_node = (const float*)d_in[0];
  const float* q_node = (const float*)d_in[1];
  const int*   qq     = (const int*)d_in[2];
  const int*   dq     = (const int*)d_in[3];
  const int*   dd     = (const int*)d_in[4];
  const int*   qd     = (const int*)d_in[5];
  const float* W_nw   = (const float*)d_in[6];
  const float* b_nw   = (const float*)d_in[7];
  const float* W_self = (const float*)d_in[8];
  const float* b_self = (const float*)d_in[9];
  const float* W_dd   = (const float*)d_in[10];
  const float* W_qq   = (const float*)d_in[11];
  const float* W_dq   = (const float*)d_in[12];
  const float* W_qd   = (const float*)d_in[13];

  float* outd = (float*)d_out;                  // [B,Ld,D]
  float* outq = outd + (size_t)MD * DIM;        // [B,Lq,D]
  float* adw  = outq + (size_t)MQ * DIM;        // [B,STEPS,Ld]
  float* aqw  = adw + (size_t)B_ * STEPS * LD;  // [B,STEPS,Lq]

  char* p = (char*)d_ws;
  auto alloc = [&](size_t bytes) { char* r = p; p += (bytes + 255) & ~(size_t)255; return r; };
  h16* dnode[2], *qnode[2];
  dnode[0] = (h16*)alloc((size_t)MD * DIM * 2);
  dnode[1] = (h16*)alloc((size_t)MD * DIM * 2);
  qnode[0] = (h16*)alloc((size_t)MQ * DIM * 2);
  qnode[1] = (h16*)alloc((size_t)MQ * DIM * 2);
  h16* catD    = (h16*)alloc((size_t)1536 * 512 * 2);
  h16* catQ    = (h16*)alloc((size_t)1536 * 512 * 2);
  h16* maskD   = (h16*)alloc((size_t)B_ * LD * KST * 2);
  h16* maskQ   = (h16*)alloc((size_t)B_ * LQ * KST * 2);
  h16* stackDT = (h16*)alloc((size_t)B_ * 512 * KST * 2);
  h16* stackQT = (h16*)alloc((size_t)B_ * 512 * KST * 2);
  float* d_wb  = (float*)alloc((size_t)MD * 4);
  float* q_wb  = (float*)alloc((size_t)MQ * 4);

  // one-time prep
  k_convert<<<dim3((MD * DIM + MQ * DIM) / 4 / 256), 256, 0, stream>>>(d_node, q_node, dnode[0], qnode[0]);
  k_wcat<<<dim3(1536 * 512 / 256), 256, 0, stream>>>(W_self, W_dd, W_qd, W_qq, W_dq, catD, catQ);
  k_maskD<<<dim3(MD / 4), 256, 0, stream>>>(dd, dq, maskD);
  k_maskQ<<<dim3(MQ / 4), 256, 0, stream>>>(qq, qd, maskQ);

  for (int it = 0; it < STEPS; it++) {
    const bool last = (it == STEPS - 1);
    h16* ncur_d = dnode[it & 1];
    h16* nnext_d = dnode[(it & 1) ^ 1];
    h16* ncur_q = qnode[it & 1];
    h16* nnext_q = qnode[(it & 1) ^ 1];

    k_w<<<dim3((MD + MQ) / 4), 256, 0, stream>>>(ncur_d, ncur_q, W_nw, b_nw, d_wb, q_wb, adw, aqw, it);

    // dense-D: A = catD rows [512,1536) = [W_dd|W_qd], Bt = dnode (all batches)
    {
      Src sa{catD + 512 * 512, 512, 0, catD + 512 * 512, 512, 0, 512};
      Src sb{ncur_d, 512, 0, ncur_d, 512, 0, 512};
      gemm2<<<dim3(1024 / 128, MD / 128, 1), 256, 0, stream>>>(
          sa, sb, 512, EpiDense{d_wb, stackDT, stackQT, 9, 0, 128});
    }
    // dense-Q: A = catQ rows [512,1536) = [W_qq|W_dq], Bt = qnode
    {
      Src sa{catQ + 512 * 512, 512, 0, catQ + 512 * 512, 512, 0, 512};
      Src sb{ncur_q, 512, 0, ncur_q, 512, 0, 512};
      gemm2<<<dim3(1024 / 128, MQ / 128, 1), 256, 0, stream>>>(
          sa, sb, 512, EpiDense{q_wb, stackQT, stackDT, 7, 0, 512});
    }
    // agg-D: A = [maskD'|dnode], Bt = [stackDT|W_self(catD rows 0..512)]
    {
      Src sa{maskD, 640, (long)LD * KST, ncur_d, 512, (long)LD * DIM, KST};
      Src sb{stackDT, 640, (long)512 * KST, catD, 512, 0, KST};
      gemm2<<<dim3(LD / 128, 512 / 128, B_), 256, 0, stream>>>(
          sa, sb, KAGG, EpiAgg{b_self, last ? outd : nullptr, nnext_d, 512});
    }
    // agg-Q: A = [maskQ'|qnode], Bt = [stackQT|W_self(catQ rows 0..512)]
    {
      Src sa{maskQ, 640, (long)LQ * KST, ncur_q, 512, (long)LQ * DIM, KST};
      Src sb{stackQT, 640, (long)512 * KST, catQ, 512, 0, KST};
      gemm2<<<dim3(LQ / 128, 512 / 128, B_), 256, 0, stream>>>(
          sa, sb, KAGG, EpiAgg{b_self, last ? outq : nullptr, nnext_q, 128});
    }
  }
}

// Round 4
// 657.373 us; speedup vs baseline: 1.4545x; 1.0962x over previous
//
#include <hip/hip_runtime.h>
#include <cstdint>
#include <cstddef>

typedef _Float16 h16;
typedef __attribute__((ext_vector_type(8))) _Float16 h16x8;
typedef __attribute__((ext_vector_type(4))) _Float16 h16x4;
typedef __attribute__((ext_vector_type(4))) float f32x4;

constexpr int B_ = 64, LD = 512, LQ = 128, DIM = 512, STEPS = 2;
constexpr int MD = B_ * LD;   // 32768 d-rows total
constexpr int MQ = B_ * LQ;   // 8192 q-rows total
constexpr int KST = LD + LQ;  // 640 stacked-neighbor K
constexpr int KAGG = KST + DIM;  // 1152 = mask|node augmented K for agg GEMM

// A GEMM operand that switches source at k = ksplit (both K-contiguous).
struct Src {
  const h16* p0; int s0; long bstr0;  // rows for k in [0, ksplit)
  const h16* p1; int s1; long bstr1;  // rows for k in [ksplit, K)
  int ksplit;
};

// ---------------------------------------------------------------------------
// C = A * B^T, f16 in, fp32 MFMA accum. Block 256 = 4 waves, tile 128x128,
// wave 64x64 via 4x4 mfma_f32_16x16x32_f16. K%64==0 (even tile count).
// Double-buffered LDS + register prefetch, ONE barrier per K-iter:
//   sync -> ds_read frags(buf c) -> ds_write regs(buf c^1) -> global load t+2
//        -> 16 MFMA
// Global-load latency overlaps a full iteration before its vmcnt wait.
// LDS swizzle (per 128x32 tile): 16B chunk (row,kq) at chunk index
//   p = 128*kq + (row ^ (2*kq)) — conflict-free for both ds_write_b128
// staging and ds_read_b128 fragment reads (verified by bank arithmetic).
// MFMA 16x16x32 layouts (measured, m89/m91):
//   A-frag: m = lane&15, k = quad*8 + j ; B-frag: n = lane&15, k = quad*8+j
//   C/D:    col(n) = lane&15, row(m) = quad*4 + r
// ---------------------------------------------------------------------------
template <class Epi>
__global__ __launch_bounds__(256) void gemm2(Src sa, Src sb, int K, Epi epi) {
  const int b = blockIdx.z;

  // [c][A/B][4096 h16]: 2 buffers x (8 KB A + 8 KB B) = 32 KB
  __shared__ __align__(16) h16 lds[2 * 2 * 4096];

  const int tid = threadIdx.x;
  const int lane = tid & 63;
  const int wv = tid >> 6;
  const int wm = (wv >> 1) * 64, wn = (wv & 1) * 64;
  const int quad = lane >> 4, l16 = lane & 15;
  const long tileM = (long)blockIdx.x * 128, tileN = (long)blockIdx.y * 128;
  const int r = tid >> 2;        // staging row (0..63)
  const int kq = tid & 3;        // staging k-quarter

  // global staging pointers (lo = row r, hi = row r+64), per source
  const h16* pa0 = sa.p0 + (size_t)b * sa.bstr0 + (tileM + r) * (long)sa.s0 + kq * 8;
  const h16* pa0h = pa0 + 64L * sa.s0;
  const h16* pa1 = sa.p1 + (size_t)b * sa.bstr1 + (tileM + r) * (long)sa.s1 + kq * 8 - sa.ksplit;
  const h16* pa1h = pa1 + 64L * sa.s1;
  const h16* pb0 = sb.p0 + (size_t)b * sb.bstr0 + (tileN + r) * (long)sb.s0 + kq * 8;
  const h16* pb0h = pb0 + 64L * sb.s0;
  const h16* pb1 = sb.p1 + (size_t)b * sb.bstr1 + (tileN + r) * (long)sb.s1 + kq * 8 - sb.ksplit;
  const h16* pb1h = pb1 + 64L * sb.s1;

  // LDS staging destinations (swizzled chunk index); row+64 -> chunk+64
  const int pw = (kq * 128 + (r ^ (2 * kq))) * 8;
  h16* const dA = &lds[pw];          // + c*8192
  h16* const dB = &lds[4096 + pw];   // + c*8192

  // fragment LDS base pointers (buf 0)
  const h16* fA[4];
  const h16* fB[4];
#pragma unroll
  for (int t = 0; t < 4; t++) {
    const int rowA = wm + t * 16 + l16;
    const int rowB = wn + t * 16 + l16;
    fA[t] = &lds[(quad * 128 + (rowA ^ (2 * quad))) * 8];
    fB[t] = &lds[4096 + (quad * 128 + (rowB ^ (2 * quad))) * 8];
  }

  f32x4 acc[4][4] = {};
  const int T = K >> 5;

  h16x8 ra0, ra1, rb0, rb1;  // prefetch registers
  auto loadT = [&](int t) {
    const int k0 = t * 32;
    const bool fa = k0 < sa.ksplit;
    ra0 = *(const h16x8*)((fa ? pa0 : pa1) + k0);
    ra1 = *(const h16x8*)((fa ? pa0h : pa1h) + k0);
    const bool fb = k0 < sb.ksplit;
    rb0 = *(const h16x8*)((fb ? pb0 : pb1) + k0);
    rb1 = *(const h16x8*)((fb ? pb0h : pb1h) + k0);
  };

  // prologue: tile 0 -> LDS[0]; tile 1 -> regs
  loadT(0);
  *(h16x8*)dA = ra0;
  *(h16x8*)(dA + 64 * 8) = ra1;
  *(h16x8*)dB = rb0;
  *(h16x8*)(dB + 64 * 8) = rb1;
  loadT(1);

  auto step = [&](int t, int c) {
    __syncthreads();
    h16x8 af[4], bf[4];
    const int off = c * 8192;
#pragma unroll
    for (int i = 0; i < 4; i++) {
      af[i] = *(const h16x8*)(fA[i] + off);
      bf[i] = *(const h16x8*)(fB[i] + off);
    }
    if (t + 1 < T) {  // stage prefetched tile t+1 into the other buffer
      const int o2 = (c ^ 1) * 8192;
      *(h16x8*)(dA + o2) = ra0;
      *(h16x8*)(dA + o2 + 64 * 8) = ra1;
      *(h16x8*)(dB + o2) = rb0;
      *(h16x8*)(dB + o2 + 64 * 8) = rb1;
    }
    if (t + 2 < T) loadT(t + 2);  // issue next global loads (latency hidden)
#pragma unroll
    for (int i = 0; i < 4; i++)
#pragma unroll
      for (int j = 0; j < 4; j++)
        acc[i][j] = __builtin_amdgcn_mfma_f32_16x16x32_f16(af[i], bf[j], acc[i][j], 0, 0, 0);
  };

  for (int t = 0; t < T; t += 2) {  // T is even for all our shapes
    step(t, 0);
    step(t + 1, 1);
  }

#pragma unroll
  for (int i = 0; i < 4; i++) {
#pragma unroll
    for (int j = 0; j < 4; j++) {
      const int gm0 = (int)tileM + wm + i * 16 + quad * 4;
      const int gn  = (int)tileN + wn + j * 16 + l16;
#pragma unroll
      for (int rr = 0; rr < 4; rr++) epi(b, gm0 + rr, gn, acc[i][j][rr]);
    }
  }
}

// --- epilogues --------------------------------------------------------------
// Dense GEMM: A = [W_x|W_y] (1024 rows), Bt = node (all batches), C[o][node].
// Writes w[node]-scaled info into stack rows (lane-contiguous along node).
struct EpiDense {
  const float* w;   // gate per node (indexed by gn)
  h16* stackA;      // gm <  512 -> stackA[b][gm][offA + l]
  h16* stackB;      // gm >= 512 -> stackB[b][gm-512][offB + l]
  int lnShift;      // nodes-per-batch shift: 9 (d) or 7 (q)
  int offA, offB;
  __device__ void operator()(int, int gm, int gn, float v) const {
    const int b = gn >> lnShift, l = gn & ((1 << lnShift) - 1);
    const h16 sv = (h16)(w[gn] * v);
    if (gm < 512)
      stackA[((size_t)b * 512 + gm) * 640 + offA + l] = sv;
    else
      stackB[((size_t)b * 512 + (gm - 512)) * 640 + offB + l] = sv;
  }
};
// Agg GEMM: A = [mask'|node], Bt = [stackT|W_self], C[i][c] = self + msg/nb.
struct EpiAgg {
  const float* bias;  // b_self[c]
  float* out;         // fp32 final output or nullptr
  h16* nodeNext;      // next-iteration node buffer [i][c]
  int rowsPerB;       // 512 (d) or 128 (q)
  __device__ void operator()(int b, int gm, int gn, float v) const {
    const size_t row = (size_t)b * rowsPerB + gm;
    const float val = fmaxf(v + bias[gn], 0.f);
    if (out) out[row * 512 + gn] = val;
    nodeNext[row * 512 + gn] = (h16)val;
  }
};

// --- small kernels ----------------------------------------------------------
__global__ __launch_bounds__(256) void k_convert(const float* __restrict__ dn,
                                                 const float* __restrict__ qn,
                                                 h16* __restrict__ dnb,
                                                 h16* __restrict__ qnb) {
  const size_t i4 = ((size_t)blockIdx.x * 256 + threadIdx.x) * 4;
  constexpr size_t TD = (size_t)MD * DIM;
  const float* src; h16* dst; size_t idx;
  if (i4 < TD) { src = dn; dst = dnb; idx = i4; }
  else         { src = qn; dst = qnb; idx = i4 - TD; }
  const float4 v = *(const float4*)&src[idx];
  h16x4 o; o.x = (h16)v.x; o.y = (h16)v.y; o.z = (h16)v.z; o.w = (h16)v.w;
  *(h16x4*)&dst[idx] = o;
}

__global__ __launch_bounds__(256) void k_wcat(const float* __restrict__ Wself,
                                              const float* __restrict__ Wdd,
                                              const float* __restrict__ Wqd,
                                              const float* __restrict__ Wqq,
                                              const float* __restrict__ Wdq,
                                              h16* __restrict__ catD,
                                              h16* __restrict__ catQ) {
  const int i = blockIdx.x * 256 + threadIdx.x;  // < 1536*512
  float vD, vQ;
  if (i < 512 * 512)       { vD = Wself[i];            vQ = vD; }
  else if (i < 1024 * 512) { vD = Wdd[i - 512 * 512];  vQ = Wqq[i - 512 * 512]; }
  else                     { vD = Wqd[i - 1024 * 512]; vQ = Wdq[i - 1024 * 512]; }
  catD[i] = (h16)vD; catQ[i] = (h16)vQ;
}

// maskD'[b][i][j] = graph/nb : j<512 dd, else dq (premultiplied by 1/max(nb,1))
__global__ __launch_bounds__(256) void k_maskD(const int* __restrict__ dd,
                                               const int* __restrict__ dq,
                                               h16* __restrict__ maskD) {
  const int row = blockIdx.x * 4 + (threadIdx.x >> 6);
  const int lane = threadIdx.x & 63;
  const int* pdd = dd + (size_t)row * 512;
  const int* pdq = dq + (size_t)row * 128;
  h16* pm = maskD + (size_t)row * 640;
  float vals[10];
  float s = 0.f;
#pragma unroll
  for (int t = 0; t < 10; t++) {
    const int j = lane + t * 64;
    const float v = (float)((j < 512) ? pdd[j] : pdq[j - 512]);
    vals[t] = v; s += v;
  }
  for (int m = 32; m; m >>= 1) s += __shfl_xor(s, m);
  const float inv = 1.f / fmaxf(s, 1.f);
#pragma unroll
  for (int t = 0; t < 10; t++) pm[lane + t * 64] = (h16)(vals[t] * inv);
}

__global__ __launch_bounds__(256) void k_maskQ(const int* __restrict__ qq,
                                               const int* __restrict__ qd,
                                               h16* __restrict__ maskQ) {
  const int row = blockIdx.x * 4 + (threadIdx.x >> 6);
  const int lane = threadIdx.x & 63;
  const int* pqq = qq + (size_t)row * 128;
  const int* pqd = qd + (size_t)row * 512;
  h16* pm = maskQ + (size_t)row * 640;
  float vals[10];
  float s = 0.f;
#pragma unroll
  for (int t = 0; t < 10; t++) {
    const int j = lane + t * 64;
    const float v = (float)((j < 128) ? pqq[j] : pqd[j - 128]);
    vals[t] = v; s += v;
  }
  for (int m = 32; m; m >>= 1) s += __shfl_xor(s, m);
  const float inv = 1.f / fmaxf(s, 1.f);
#pragma unroll
  for (int t = 0; t < 10; t++) pm[lane + t * 64] = (h16)(vals[t] * inv);
}

// sigmoid gate per node row: one wave per row (d rows then q rows)
__global__ __launch_bounds__(256) void k_w(const h16* __restrict__ dnb,
                                           const h16* __restrict__ qnb,
                                           const float* __restrict__ Wnw,
                                           const float* __restrict__ bnw,
                                           float* __restrict__ d_w,
                                           float* __restrict__ q_w,
                                           float* __restrict__ adw,
                                           float* __restrict__ aqw, int it) {
  const int row = blockIdx.x * 4 + (threadIdx.x >> 6);
  const int lane = threadIdx.x & 63;
  const bool isD = row < MD;
  const h16* node = isD ? dnb + (size_t)row * 512 : qnb + (size_t)(row - MD) * 512;
  const h16x8 v = *(const h16x8*)&node[lane * 8];
  const float4 w0 = *(const float4*)&Wnw[lane * 8];
  const float4 w1 = *(const float4*)&Wnw[lane * 8 + 4];
  float s = (float)v[0] * w0.x + (float)v[1] * w0.y + (float)v[2] * w0.z +
            (float)v[3] * w0.w + (float)v[4] * w1.x + (float)v[5] * w1.y +
            (float)v[6] * w1.z + (float)v[7] * w1.w;
  for (int m = 32; m; m >>= 1) s += __shfl_xor(s, m);
  if (lane == 0) {
    const float w = 1.f / (1.f + expf(-(s + bnw[0])));
    if (isD) {
      d_w[row] = w;
      adw[((size_t)(row >> 9) * STEPS + it) * 512 + (row & 511)] = w;
    } else {
      const int rq = row - MD;
      q_w[rq] = w;
      aqw[((size_t)(rq >> 7) * STEPS + it) * 128 + (rq & 127)] = w;
    }
  }
}

// ---------------------------------------------------------------------------
extern "C" void kernel_launch(void* const* d_in, const int* in_sizes, int n_in,
                              void* d_out, int out_size, void* d_ws, size_t ws_size,
                              hipStream_t stream) {
  (void)in_sizes; (void)n_in; (void)out_size; (void)ws_size;

  const float* d_node = (const float*)d_in[0];
  const float* q_node = (const float*)d_in[1];
  const int*   qq     = (const int*)d_in[2];
  const int*   dq     = (const int*)d_in[3];
  const int*   dd     = (const int*)d_in[4];
  const int*   qd     = (const int*)d_in[5];
  const float* W_nw   = (const float*)d_in[6];
  const float* b_nw   = (const float*)d_in[7];
  const float* W_self = (const float*)d_in[8];
  const float* b_self = (const float*)d_in[9];
  const float* W_dd   = (const float*)d_in[10];
  const float* W_qq   = (const float*)d_in[11];
  const float* W_dq   = (const float*)d_in[12];
  const float* W_qd   = (const float*)d_in[13];

  float* outd = (float*)d_out;                  // [B,Ld,D]
  float* outq = outd + (size_t)MD * DIM;        // [B,Lq,D]
  float* adw  = outq + (size_t)MQ * DIM;        // [B,STEPS,Ld]
  float* aqw  = adw + (size_t)B_ * STEPS * LD;  // [B,STEPS,Lq]

  char* p = (char*)d_ws;
  auto alloc = [&](size_t bytes) { char* r = p; p += (bytes + 255) & ~(size_t)255; return r; };
  h16* dnode[2], *qnode[2];
  dnode[0] = (h16*)alloc((size_t)MD * DIM * 2);
  dnode[1] = (h16*)alloc((size_t)MD * DIM * 2);
  qnode[0] = (h16*)alloc((size_t)MQ * DIM * 2);
  qnode[1] = (h16*)alloc((size_t)MQ * DIM * 2);
  h16* catD    = (h16*)alloc((size_t)1536 * 512 * 2);
  h16* catQ    = (h16*)alloc((size_t)1536 * 512 * 2);
  h16* maskD   = (h16*)alloc((size_t)B_ * LD * KST * 2);
  h16* maskQ   = (h16*)alloc((size_t)B_ * LQ * KST * 2);
  h16* stackDT = (h16*)alloc((size_t)B_ * 512 * KST * 2);
  h16* stackQT = (h16*)alloc((size_t)B_ * 512 * KST * 2);
  float* d_wb  = (float*)alloc((size_t)MD * 4);
  float* q_wb  = (float*)alloc((size_t)MQ * 4);

  // one-time prep
  k_convert<<<dim3((MD * DIM + MQ * DIM) / 4 / 256), 256, 0, stream>>>(d_node, q_node, dnode[0], qnode[0]);
  k_wcat<<<dim3(1536 * 512 / 256), 256, 0, stream>>>(W_self, W_dd, W_qd, W_qq, W_dq, catD, catQ);
  k_maskD<<<dim3(MD / 4), 256, 0, stream>>>(dd, dq, maskD);
  k_maskQ<<<dim3(MQ / 4), 256, 0, stream>>>(qq, qd, maskQ);

  for (int it = 0; it < STEPS; it++) {
    const bool last = (it == STEPS - 1);
    h16* ncur_d = dnode[it & 1];
    h16* nnext_d = dnode[(it & 1) ^ 1];
    h16* ncur_q = qnode[it & 1];
    h16* nnext_q = qnode[(it & 1) ^ 1];

    k_w<<<dim3((MD + MQ) / 4), 256, 0, stream>>>(ncur_d, ncur_q, W_nw, b_nw, d_wb, q_wb, adw, aqw, it);

    // dense-D: A = catD rows [512,1536) = [W_dd|W_qd], Bt = dnode (all batches)
    {
      Src sa{catD + 512 * 512, 512, 0, catD + 512 * 512, 512, 0, 512};
      Src sb{ncur_d, 512, 0, ncur_d, 512, 0, 512};
      gemm2<<<dim3(1024 / 128, MD / 128, 1), 256, 0, stream>>>(
          sa, sb, 512, EpiDense{d_wb, stackDT, stackQT, 9, 0, 128});
    }
    // dense-Q: A = catQ rows [512,1536) = [W_qq|W_dq], Bt = qnode
    {
      Src sa{catQ + 512 * 512, 512, 0, catQ + 512 * 512, 512, 0, 512};
      Src sb{ncur_q, 512, 0, ncur_q, 512, 0, 512};
      gemm2<<<dim3(1024 / 128, MQ / 128, 1), 256, 0, stream>>>(
          sa, sb, 512, EpiDense{q_wb, stackQT, stackDT, 7, 0, 512});
    }
    // agg-D: A = [maskD'|dnode], Bt = [stackDT|W_self(catD rows 0..512)]
    {
      Src sa{maskD, 640, (long)LD * KST, ncur_d, 512, (long)LD * DIM, KST};
      Src sb{stackDT, 640, (long)512 * KST, catD, 512, 0, KST};
      gemm2<<<dim3(LD / 128, 512 / 128, B_), 256, 0, stream>>>(
          sa, sb, KAGG, EpiAgg{b_self, last ? outd : nullptr, nnext_d, 512});
    }
    // agg-Q: A = [maskQ'|qnode], Bt = [stackQT|W_self(catQ rows 0..512)]
    {
      Src sa{maskQ, 640, (long)LQ * KST, ncur_q, 512, (long)LQ * DIM, KST};
      Src sb{stackQT, 640, (long)512 * KST, catQ, 512, 0, KST};
      gemm2<<<dim3(LQ / 128, 512 / 128, B_), 256, 0, stream>>>(
          sa, sb, KAGG, EpiAgg{b_self, last ? outq : nullptr, nnext_q, 128});
    }
  }
}

// Round 5
// 627.149 us; speedup vs baseline: 1.5246x; 1.0482x over previous
//
#include <hip/hip_runtime.h>
#include <cstdint>
#include <cstddef>

typedef _Float16 h16;
typedef __attribute__((ext_vector_type(8))) _Float16 h16x8;
typedef __attribute__((ext_vector_type(4))) _Float16 h16x4;
typedef __attribute__((ext_vector_type(4))) float f32x4;

constexpr int B_ = 64, LD = 512, LQ = 128, DIM = 512, STEPS = 2;
constexpr int MD = B_ * LD;   // 32768 d-rows total
constexpr int MQ = B_ * LQ;   // 8192 q-rows total
constexpr int KST = LD + LQ;  // 640 stacked-neighbor K
constexpr int KAGG = KST + DIM;  // 1152 = mask|node augmented K for agg GEMM

// A GEMM operand that switches source at k = ksplit (both K-contiguous).
struct Src {
  const h16* p0; int s0; long bstr0;  // rows for k in [0, ksplit)
  const h16* p1; int s1; long bstr1;  // rows for k in [ksplit, K)
  int ksplit;
};

// ---------------------------------------------------------------------------
// Core: C = A * B^T 128x128 tile, f16 in, fp32 MFMA accum, 4 waves.
// Double-buffered LDS, TWO register prefetch sets (loads issued 3 iters ahead
// of LDS-write, 2 iters ahead of consumption) — covers L2 (~200c) and most
// HBM (~900c) latency. One barrier per K-iter.
// LDS swizzle (per 128x32 tile): 16B chunk (row,kq) at chunk index
//   p = 128*kq + (row ^ (2*kq)) — conflict-free for ds_write_b128 staging and
// ds_read_b128 fragment reads (bank arithmetic; r3 measured 0 conflicts).
// MFMA 16x16x32 layouts (measured, m89/m91):
//   A-frag: m = lane&15, k = quad*8 + j ; B-frag: n = lane&15, k = quad*8+j
//   C/D:    col(n) = lane&15, row(m) = quad*4 + r
// ---------------------------------------------------------------------------
template <class Epi>
__device__ __forceinline__ void gemm_body(int b, long tileM, long tileN,
                                          Src sa, Src sb, int K,
                                          const Epi& epi, h16* lds) {
  const int tid = threadIdx.x;
  const int lane = tid & 63;
  const int wv = tid >> 6;
  const int wm = (wv >> 1) * 64, wn = (wv & 1) * 64;
  const int quad = lane >> 4, l16 = lane & 15;
  const int r = tid >> 2;        // staging row (0..63)
  const int kq = tid & 3;        // staging k-quarter

  // global staging pointers (lo = row r, hi = row r+64), per source
  const h16* pa0 = sa.p0 + (size_t)b * sa.bstr0 + (tileM + r) * (long)sa.s0 + kq * 8;
  const h16* pa0h = pa0 + 64L * sa.s0;
  const h16* pa1 = sa.p1 + (size_t)b * sa.bstr1 + (tileM + r) * (long)sa.s1 + kq * 8 - sa.ksplit;
  const h16* pa1h = pa1 + 64L * sa.s1;
  const h16* pb0 = sb.p0 + (size_t)b * sb.bstr0 + (tileN + r) * (long)sb.s0 + kq * 8;
  const h16* pb0h = pb0 + 64L * sb.s0;
  const h16* pb1 = sb.p1 + (size_t)b * sb.bstr1 + (tileN + r) * (long)sb.s1 + kq * 8 - sb.ksplit;
  const h16* pb1h = pb1 + 64L * sb.s1;

  // LDS staging destinations (swizzled chunk index); row+64 -> chunk+64
  const int pw = (kq * 128 + (r ^ (2 * kq))) * 8;
  h16* const dA = &lds[pw];          // + c*8192
  h16* const dB = &lds[4096 + pw];   // + c*8192

  // fragment LDS base pointers (buf 0)
  const h16* fA[4];
  const h16* fB[4];
#pragma unroll
  for (int t = 0; t < 4; t++) {
    const int rowA = wm + t * 16 + l16;
    const int rowB = wn + t * 16 + l16;
    fA[t] = &lds[(quad * 128 + (rowA ^ (2 * quad))) * 8];
    fB[t] = &lds[4096 + (quad * 128 + (rowB ^ (2 * quad))) * 8];
  }

  f32x4 acc[4][4] = {};
  const int T = K >> 5;  // even for all our shapes (16 or 36)

  h16x8 s0[4], s1[4];  // two prefetch sets
  auto loadInto = [&](h16x8* s, int t) {
    const int k0 = t * 32;
    const bool fa = k0 < sa.ksplit;
    s[0] = *(const h16x8*)((fa ? pa0 : pa1) + k0);
    s[1] = *(const h16x8*)((fa ? pa0h : pa1h) + k0);
    const bool fb = k0 < sb.ksplit;
    s[2] = *(const h16x8*)((fb ? pb0 : pb1) + k0);
    s[3] = *(const h16x8*)((fb ? pb0h : pb1h) + k0);
  };
  auto writeLDS = [&](const h16x8* s, int c) {
    const int o = c * 8192;
    *(h16x8*)(dA + o) = s[0];
    *(h16x8*)(dA + o + 512) = s[1];
    *(h16x8*)(dB + o) = s[2];
    *(h16x8*)(dB + o + 512) = s[3];
  };
  auto mfma16 = [&](const int off) {
    h16x8 af[4], bf[4];
#pragma unroll
    for (int i = 0; i < 4; i++) {
      af[i] = *(const h16x8*)(fA[i] + off);
      bf[i] = *(const h16x8*)(fB[i] + off);
    }
#pragma unroll
    for (int i = 0; i < 4; i++)
#pragma unroll
      for (int j = 0; j < 4; j++)
        acc[i][j] = __builtin_amdgcn_mfma_f32_16x16x32_f16(af[i], bf[j], acc[i][j], 0, 0, 0);
  };

  // prologue: tile0 -> buf0; tile1 -> s0; tile2 -> s1
  loadInto(s0, 0);
  writeLDS(s0, 0);
  loadInto(s0, 1);
  if (2 < T) loadInto(s1, 2);

  for (int t = 0; t < T; t += 2) {
    // even step: consume buf0; stage tile t+1 (in s0) -> buf1; load t+3 -> s0
    __syncthreads();
    {
      h16x8 af[4], bf[4];
#pragma unroll
      for (int i = 0; i < 4; i++) { af[i] = *(const h16x8*)fA[i]; bf[i] = *(const h16x8*)fB[i]; }
      writeLDS(s0, 1);
      if (t + 3 < T) loadInto(s0, t + 3);
#pragma unroll
      for (int i = 0; i < 4; i++)
#pragma unroll
        for (int j = 0; j < 4; j++)
          acc[i][j] = __builtin_amdgcn_mfma_f32_16x16x32_f16(af[i], bf[j], acc[i][j], 0, 0, 0);
    }
    // odd step: consume buf1; stage tile t+2 (in s1) -> buf0; load t+4 -> s1
    __syncthreads();
    {
      h16x8 af[4], bf[4];
#pragma unroll
      for (int i = 0; i < 4; i++) { af[i] = *(const h16x8*)(fA[i] + 8192); bf[i] = *(const h16x8*)(fB[i] + 8192); }
      if (t + 2 < T) writeLDS(s1, 0);
      if (t + 4 < T) loadInto(s1, t + 4);
#pragma unroll
      for (int i = 0; i < 4; i++)
#pragma unroll
        for (int j = 0; j < 4; j++)
          acc[i][j] = __builtin_amdgcn_mfma_f32_16x16x32_f16(af[i], bf[j], acc[i][j], 0, 0, 0);
    }
  }

#pragma unroll
  for (int i = 0; i < 4; i++) {
#pragma unroll
    for (int j = 0; j < 4; j++) {
      const int gm0 = (int)tileM + wm + i * 16 + quad * 4;
      const int gn  = (int)tileN + wn + j * 16 + l16;
#pragma unroll
      for (int rr = 0; rr < 4; rr++) epi(b, gm0 + rr, gn, acc[i][j][rr]);
    }
  }
}

// --- epilogues --------------------------------------------------------------
// Dense GEMM: A = [W_x|W_y] (1024 rows), Bt = node (all batches), C[o][node].
// Writes w[node]-scaled info into stack rows (lane-contiguous along node).
struct EpiDense {
  const float* w;   // gate per node (indexed by gn)
  h16* stackA;      // gm <  512 -> stackA[b][gm][offA + l]
  h16* stackB;      // gm >= 512 -> stackB[b][gm-512][offB + l]
  int lnShift;      // nodes-per-batch shift: 9 (d) or 7 (q)
  int offA, offB;
  __device__ void operator()(int, int gm, int gn, float v) const {
    const int b = gn >> lnShift, l = gn & ((1 << lnShift) - 1);
    const h16 sv = (h16)(w[gn] * v);
    if (gm < 512)
      stackA[((size_t)b * 512 + gm) * 640 + offA + l] = sv;
    else
      stackB[((size_t)b * 512 + (gm - 512)) * 640 + offB + l] = sv;
  }
};
// Agg GEMM: A = [mask'|node], Bt = [stackT|W_self], C[i][c] = self + msg/nb.
struct EpiAgg {
  const float* bias;  // b_self[c]
  float* out;         // fp32 final output or nullptr
  h16* nodeNext;      // next-iteration node buffer [i][c]
  int rowsPerB;       // 512 (d) or 128 (q)
  __device__ void operator()(int b, int gm, int gn, float v) const {
    const size_t row = (size_t)b * rowsPerB + gm;
    const float val = fmaxf(v + bias[gn], 0.f);
    if (out) out[row * 512 + gn] = val;
    nodeNext[row * 512 + gn] = (h16)val;
  }
};

// ---------------------------------------------------------------------------
// Combined dense launch: 2560 blocks. g = x*320 + yy; x = M-tile (0..7),
// yy<256 -> d-job (tileN=yy*128 into dnode), else q-job (yy-256).
// Same-yy blocks are 320 apart => same id%8 => same XCD (L2 reuse of B-tile).
// ---------------------------------------------------------------------------
__global__ __launch_bounds__(256) void k_dense(Src saD, Src sbD, EpiDense epiD,
                                               Src saQ, Src sbQ, EpiDense epiQ) {
  __shared__ __align__(16) h16 lds[2 * 2 * 4096];
  const int g = blockIdx.x;
  const int x = g / 320;
  const int yy = g % 320;
  if (yy < 256)
    gemm_body(0, (long)x * 128, (long)yy * 128, saD, sbD, 512, epiD, lds);
  else
    gemm_body(0, (long)x * 128, (long)(yy - 256) * 128, saQ, sbQ, 512, epiQ, lds);
}

// Combined agg launch: 1280 blocks. g = inner*64 + b; inner<16 -> d-job
// (x=inner>>2, y=inner&3), else q-job (x=0, y=inner-16).
// Same-batch blocks are 64 apart => same XCD (per-batch ~3MB ~ L2).
__global__ __launch_bounds__(256) void k_agg(Src saD, Src sbD, EpiAgg epiD,
                                             Src saQ, Src sbQ, EpiAgg epiQ) {
  __shared__ __align__(16) h16 lds[2 * 2 * 4096];
  const int g = blockIdx.x;
  const int b = g & 63;
  const int inner = g >> 6;
  if (inner < 16)
    gemm_body(b, (long)(inner >> 2) * 128, (long)(inner & 3) * 128, saD, sbD, KAGG, epiD, lds);
  else
    gemm_body(b, 0L, (long)(inner - 16) * 128, saQ, sbQ, KAGG, epiQ, lds);
}

// --- small kernels ----------------------------------------------------------
__global__ __launch_bounds__(256) void k_convert(const float* __restrict__ dn,
                                                 const float* __restrict__ qn,
                                                 h16* __restrict__ dnb,
                                                 h16* __restrict__ qnb) {
  const size_t i4 = ((size_t)blockIdx.x * 256 + threadIdx.x) * 4;
  constexpr size_t TD = (size_t)MD * DIM;
  const float* src; h16* dst; size_t idx;
  if (i4 < TD) { src = dn; dst = dnb; idx = i4; }
  else         { src = qn; dst = qnb; idx = i4 - TD; }
  const float4 v = *(const float4*)&src[idx];
  h16x4 o; o.x = (h16)v.x; o.y = (h16)v.y; o.z = (h16)v.z; o.w = (h16)v.w;
  *(h16x4*)&dst[idx] = o;
}

__global__ __launch_bounds__(256) void k_wcat(const float* __restrict__ Wself,
                                              const float* __restrict__ Wdd,
                                              const float* __restrict__ Wqd,
                                              const float* __restrict__ Wqq,
                                              const float* __restrict__ Wdq,
                                              h16* __restrict__ catD,
                                              h16* __restrict__ catQ) {
  const int i = blockIdx.x * 256 + threadIdx.x;  // < 1536*512
  float vD, vQ;
  if (i < 512 * 512)       { vD = Wself[i];            vQ = vD; }
  else if (i < 1024 * 512) { vD = Wdd[i - 512 * 512];  vQ = Wqq[i - 512 * 512]; }
  else                     { vD = Wqd[i - 1024 * 512]; vQ = Wdq[i - 1024 * 512]; }
  catD[i] = (h16)vD; catQ[i] = (h16)vQ;
}

// maskD'[b][i][j] = graph/nb : j<512 dd, else dq (premultiplied by 1/max(nb,1))
__global__ __launch_bounds__(256) void k_maskD(const int* __restrict__ dd,
                                               const int* __restrict__ dq,
                                               h16* __restrict__ maskD) {
  const int row = blockIdx.x * 4 + (threadIdx.x >> 6);
  const int lane = threadIdx.x & 63;
  const int* pdd = dd + (size_t)row * 512;
  const int* pdq = dq + (size_t)row * 128;
  h16* pm = maskD + (size_t)row * 640;
  float vals[10];
  float s = 0.f;
#pragma unroll
  for (int t = 0; t < 10; t++) {
    const int j = lane + t * 64;
    const float v = (float)((j < 512) ? pdd[j] : pdq[j - 512]);
    vals[t] = v; s += v;
  }
  for (int m = 32; m; m >>= 1) s += __shfl_xor(s, m);
  const float inv = 1.f / fmaxf(s, 1.f);
#pragma unroll
  for (int t = 0; t < 10; t++) pm[lane + t * 64] = (h16)(vals[t] * inv);
}

__global__ __launch_bounds__(256) void k_maskQ(const int* __restrict__ qq,
                                               const int* __restrict__ qd,
                                               h16* __restrict__ maskQ) {
  const int row = blockIdx.x * 4 + (threadIdx.x >> 6);
  const int lane = threadIdx.x & 63;
  const int* pqq = qq + (size_t)row * 128;
  const int* pqd = qd + (size_t)row * 512;
  h16* pm = maskQ + (size_t)row * 640;
  float vals[10];
  float s = 0.f;
#pragma unroll
  for (int t = 0; t < 10; t++) {
    const int j = lane + t * 64;
    const float v = (float)((j < 128) ? pqq[j] : pqd[j - 128]);
    vals[t] = v; s += v;
  }
  for (int m = 32; m; m >>= 1) s += __shfl_xor(s, m);
  const float inv = 1.f / fmaxf(s, 1.f);
#pragma unroll
  for (int t = 0; t < 10; t++) pm[lane + t * 64] = (h16)(vals[t] * inv);
}

// sigmoid gate per node row: one wave per row (d rows then q rows)
__global__ __launch_bounds__(256) void k_w(const h16* __restrict__ dnb,
                                           const h16* __restrict__ qnb,
                                           const float* __restrict__ Wnw,
                                           const float* __restrict__ bnw,
                                           float* __restrict__ d_w,
                                           float* __restrict__ q_w,
                                           float* __restrict__ adw,
                                           float* __restrict__ aqw, int it) {
  const int row = blockIdx.x * 4 + (threadIdx.x >> 6);
  const int lane = threadIdx.x & 63;
  const bool isD = row < MD;
  const h16* node = isD ? dnb + (size_t)row * 512 : qnb + (size_t)(row - MD) * 512;
  const h16x8 v = *(const h16x8*)&node[lane * 8];
  const float4 w0 = *(const float4*)&Wnw[lane * 8];
  const float4 w1 = *(const float4*)&Wnw[lane * 8 + 4];
  float s = (float)v[0] * w0.x + (float)v[1] * w0.y + (float)v[2] * w0.z +
            (float)v[3] * w0.w + (float)v[4] * w1.x + (float)v[5] * w1.y +
            (float)v[6] * w1.z + (float)v[7] * w1.w;
  for (int m = 32; m; m >>= 1) s += __shfl_xor(s, m);
  if (lane == 0) {
    const float w = 1.f / (1.f + expf(-(s + bnw[0])));
    if (isD) {
      d_w[row] = w;
      adw[((size_t)(row >> 9) * STEPS + it) * 512 + (row & 511)] = w;
    } else {
      const int rq = row - MD;
      q_w[rq] = w;
      aqw[((size_t)(rq >> 7) * STEPS + it) * 128 + (rq & 127)] = w;
    }
  }
}

// ---------------------------------------------------------------------------
extern "C" void kernel_launch(void* const* d_in, const int* in_sizes, int n_in,
                              void* d_out, int out_size, void* d_ws, size_t ws_size,
                              hipStream_t stream) {
  (void)in_sizes; (void)n_in; (void)out_size; (void)ws_size;

  const float* d_node = (const float*)d_in[0];
  const float* q_node = (const float*)d_in[1];
  const int*   qq     = (const int*)d_in[2];
  const int*   dq     = (const int*)d_in[3];
  const int*   dd     = (const int*)d_in[4];
  const int*   qd     = (const int*)d_in[5];
  const float* W_nw   = (const float*)d_in[6];
  const float* b_nw   = (const float*)d_in[7];
  const float* W_self = (const float*)d_in[8];
  const float* b_self = (const float*)d_in[9];
  const float* W_dd   = (const float*)d_in[10];
  const float* W_qq   = (const float*)d_in[11];
  const float* W_dq   = (const float*)d_in[12];
  const float* W_qd   = (const float*)d_in[13];

  float* outd = (float*)d_out;                  // [B,Ld,D]
  float* outq = outd + (size_t)MD * DIM;        // [B,Lq,D]
  float* adw  = outq + (size_t)MQ * DIM;        // [B,STEPS,Ld]
  float* aqw  = adw + (size_t)B_ * STEPS * LD;  // [B,STEPS,Lq]

  char* p = (char*)d_ws;
  auto alloc = [&](size_t bytes) { char* r = p; p += (bytes + 255) & ~(size_t)255; return r; };
  h16* dnode[2], *qnode[2];
  dnode[0] = (h16*)alloc((size_t)MD * DIM * 2);
  dnode[1] = (h16*)alloc((size_t)MD * DIM * 2);
  qnode[0] = (h16*)alloc((size_t)MQ * DIM * 2);
  qnode[1] = (h16*)alloc((size_t)MQ * DIM * 2);
  h16* catD    = (h16*)alloc((size_t)1536 * 512 * 2);
  h16* catQ    = (h16*)alloc((size_t)1536 * 512 * 2);
  h16* maskD   = (h16*)alloc((size_t)B_ * LD * KST * 2);
  h16* maskQ   = (h16*)alloc((size_t)B_ * LQ * KST * 2);
  h16* stackDT = (h16*)alloc((size_t)B_ * 512 * KST * 2);
  h16* stackQT = (h16*)alloc((size_t)B_ * 512 * KST * 2);
  float* d_wb  = (float*)alloc((size_t)MD * 4);
  float* q_wb  = (float*)alloc((size_t)MQ * 4);

  // one-time prep
  k_convert<<<dim3((MD * DIM + MQ * DIM) / 4 / 256), 256, 0, stream>>>(d_node, q_node, dnode[0], qnode[0]);
  k_wcat<<<dim3(1536 * 512 / 256), 256, 0, stream>>>(W_self, W_dd, W_qd, W_qq, W_dq, catD, catQ);
  k_maskD<<<dim3(MD / 4), 256, 0, stream>>>(dd, dq, maskD);
  k_maskQ<<<dim3(MQ / 4), 256, 0, stream>>>(qq, qd, maskQ);

  for (int it = 0; it < STEPS; it++) {
    const bool last = (it == STEPS - 1);
    h16* ncur_d = dnode[it & 1];
    h16* nnext_d = dnode[(it & 1) ^ 1];
    h16* ncur_q = qnode[it & 1];
    h16* nnext_q = qnode[(it & 1) ^ 1];

    k_w<<<dim3((MD + MQ) / 4), 256, 0, stream>>>(ncur_d, ncur_q, W_nw, b_nw, d_wb, q_wb, adw, aqw, it);

    // combined dense: d-job A=catD[512:1536]=[W_dd|W_qd] Bt=dnode;
    //                 q-job A=catQ[512:1536]=[W_qq|W_dq] Bt=qnode
    {
      Src saD{catD + 512 * 512, 512, 0, catD + 512 * 512, 512, 0, 512};
      Src sbD{ncur_d, 512, 0, ncur_d, 512, 0, 512};
      Src saQ{catQ + 512 * 512, 512, 0, catQ + 512 * 512, 512, 0, 512};
      Src sbQ{ncur_q, 512, 0, ncur_q, 512, 0, 512};
      k_dense<<<dim3(2560), 256, 0, stream>>>(
          saD, sbD, EpiDense{d_wb, stackDT, stackQT, 9, 0, 128},
          saQ, sbQ, EpiDense{q_wb, stackQT, stackDT, 7, 0, 512});
    }
    // combined agg: d-job A=[maskD'|dnode] Bt=[stackDT|W_self];
    //               q-job A=[maskQ'|qnode] Bt=[stackQT|W_self]
    {
      Src saD{maskD, 640, (long)LD * KST, ncur_d, 512, (long)LD * DIM, KST};
      Src sbD{stackDT, 640, (long)512 * KST, catD, 512, 0, KST};
      Src saQ{maskQ, 640, (long)LQ * KST, ncur_q, 512, (long)LQ * DIM, KST};
      Src sbQ{stackQT, 640, (long)512 * KST, catQ, 512, 0, KST};
      k_agg<<<dim3(1280), 256, 0, stream>>>(
          saD, sbD, EpiAgg{b_self, last ? outd : nullptr, nnext_d, 512},
          saQ, sbQ, EpiAgg{b_self, last ? outq : nullptr, nnext_q, 128});
    }
  }
}

// Round 6
// 568.901 us; speedup vs baseline: 1.6807x; 1.1024x over previous
//
#include <hip/hip_runtime.h>
#include <cstdint>
#include <cstddef>

typedef _Float16 h16;
typedef __attribute__((ext_vector_type(8))) _Float16 h16x8;
typedef __attribute__((ext_vector_type(4))) _Float16 h16x4;
typedef __attribute__((ext_vector_type(4))) float f32x4;

constexpr int B_ = 64, LD = 512, LQ = 128, DIM = 512, STEPS = 2;
constexpr int MD = B_ * LD;   // 32768 d-rows total
constexpr int MQ = B_ * LQ;   // 8192 q-rows total
constexpr int KST = LD + LQ;  // 640 stacked-neighbor K
constexpr int KAGG = KST + DIM;  // 1152 = mask|node augmented K for agg GEMM

// async global->LDS, 16B per lane; LDS dest must be wave-uniform base + lane*16
#define ASYNC16(gp, lp)                                                          \
  __builtin_amdgcn_global_load_lds(                                              \
      (const __attribute__((address_space(1))) unsigned int*)(gp),               \
      (__attribute__((address_space(3))) unsigned int*)(lp), 16, 0, 0)

// A GEMM operand that switches source at k = ksplit (both K-contiguous).
struct Src {
  const h16* p0; int s0; long bstr0;  // rows for k in [0, ksplit)
  const h16* p1; int s1; long bstr1;  // rows for k in [ksplit, K)
  int ksplit;
};

// ---------------------------------------------------------------------------
// Core: C = A * B^T 128x128 tile, f16 in, fp32 MFMA accum, 4 waves.
// Double-buffered LDS, staged by global_load_lds width=16 (no VGPR roundtrip,
// no prefetch registers). One barrier per K-iter; DMA for tile t+1 issued
// right after the barrier of iter t and drained by the barrier of iter t+1.
//
// LDS swizzle compatible with the DMA's lane-linear destination:
//   16B chunk for (row, kq) lives at chunk index  c = row*4 + (kq ^ e(row)),
//   e(row) = (row ^ (row>>2)) & 3.
// Staging thread t writes LDS chunk t (lo rows) / t+256 (hi rows) — exactly
// base + lane*16 as the DMA requires — and fetches global (row = t>>2,
// kq = (t&3) ^ e(row)): 4 consecutive lanes still cover one 64B row segment.
// Fragment ds_read_b128 bank-quad = 4*(l16&1) + (quad ^ e(l16)) covers all 8
// bank-quads per 8-lane phase -> conflict-free (r3/r5 measured 0 conflicts
// for the equivalent arithmetic).
// MFMA 16x16x32 layouts (measured, m89/m91):
//   A-frag: m = lane&15, k = quad*8 + j ; B-frag: n = lane&15, k = quad*8+j
//   C/D:    col(n) = lane&15, row(m) = quad*4 + r
// ---------------------------------------------------------------------------
template <class Epi>
__device__ __forceinline__ void gemm_body(int b, long tileM, long tileN,
                                          Src sa, Src sb, int K,
                                          const Epi& epi, h16* lds) {
  const int tid = threadIdx.x;
  const int lane = tid & 63;
  const int wv = tid >> 6;
  const int wm = (wv >> 1) * 64, wn = (wv & 1) * 64;
  const int quad = lane >> 4, l16 = lane & 15;

  // staging mapping: thread t -> LDS chunk t; global (row, kq) per swizzle
  const int r = tid >> 2;                       // 0..63
  const int es = (r ^ (r >> 2)) & 3;
  const int kq = (tid & 3) ^ es;                // permuted k-quarter

  // global staging pointers (lo = row r, hi = row r+64; e(row+64)=e(row))
  const h16* pa0 = sa.p0 + (size_t)b * sa.bstr0 + (tileM + r) * (long)sa.s0 + kq * 8;
  const h16* pa0h = pa0 + 64L * sa.s0;
  const h16* pa1 = sa.p1 + (size_t)b * sa.bstr1 + (tileM + r) * (long)sa.s1 + kq * 8 - sa.ksplit;
  const h16* pa1h = pa1 + 64L * sa.s1;
  const h16* pb0 = sb.p0 + (size_t)b * sb.bstr0 + (tileN + r) * (long)sb.s0 + kq * 8;
  const h16* pb0h = pb0 + 64L * sb.s0;
  const h16* pb1 = sb.p1 + (size_t)b * sb.bstr1 + (tileN + r) * (long)sb.s1 + kq * 8 - sb.ksplit;
  const h16* pb1h = pb1 + 64L * sb.s1;

  // LDS staging destinations: chunk index == tid (lo) / tid+256 (hi)
  h16* const dA = &lds[tid * 8];          // + c*8192 buffer offset
  h16* const dB = &lds[4096 + tid * 8];

  // fragment LDS base pointers (buf 0); e depends only on l16
  const int ef = (l16 ^ (l16 >> 2)) & 3;
  const h16* fA[4];
  const h16* fB[4];
#pragma unroll
  for (int t = 0; t < 4; t++) {
    const int rowA = wm + t * 16 + l16;
    const int rowB = wn + t * 16 + l16;
    fA[t] = &lds[(rowA * 4 + (quad ^ ef)) * 8];
    fB[t] = &lds[4096 + (rowB * 4 + (quad ^ ef)) * 8];
  }

  f32x4 acc[4][4] = {};
  const int T = K >> 5;  // even for all our shapes (16 or 36)

  auto dmaTile = [&](int t, int c) {
    const int k0 = t * 32;
    const int o = c * 8192;
    const bool fa = k0 < sa.ksplit;
    ASYNC16((fa ? pa0 : pa1) + k0, dA + o);
    ASYNC16((fa ? pa0h : pa1h) + k0, dA + o + 2048);
    const bool fb = k0 < sb.ksplit;
    ASYNC16((fb ? pb0 : pb1) + k0, dB + o);
    ASYNC16((fb ? pb0h : pb1h) + k0, dB + o + 2048);
  };
  auto mfma16 = [&](int off) {
    h16x8 af[4], bf[4];
#pragma unroll
    for (int i = 0; i < 4; i++) {
      af[i] = *(const h16x8*)(fA[i] + off);
      bf[i] = *(const h16x8*)(fB[i] + off);
    }
#pragma unroll
    for (int i = 0; i < 4; i++)
#pragma unroll
      for (int j = 0; j < 4; j++)
        acc[i][j] = __builtin_amdgcn_mfma_f32_16x16x32_f16(af[i], bf[j], acc[i][j], 0, 0, 0);
  };

  dmaTile(0, 0);  // prologue: tile 0 -> buf0

  for (int t = 0; t < T; t += 2) {
    __syncthreads();                      // drains DMA(t -> buf0)
    dmaTile(t + 1, 1);                    // t+1 < T always (T even)
    mfma16(0);                            // consume buf0
    __syncthreads();                      // drains DMA(t+1 -> buf1)
    if (t + 2 < T) dmaTile(t + 2, 0);
    mfma16(8192);                         // consume buf1
  }

#pragma unroll
  for (int i = 0; i < 4; i++) {
#pragma unroll
    for (int j = 0; j < 4; j++) {
      const int gm0 = (int)tileM + wm + i * 16 + quad * 4;
      const int gn  = (int)tileN + wn + j * 16 + l16;
#pragma unroll
      for (int rr = 0; rr < 4; rr++) epi(b, gm0 + rr, gn, acc[i][j][rr]);
    }
  }
}

// --- epilogues --------------------------------------------------------------
// Dense GEMM: A = [W_x|W_y] (1024 rows), Bt = node (all batches), C[o][node].
// Writes w[node]-scaled info into stack rows (lane-contiguous along node).
struct EpiDense {
  const float* w;   // gate per node (indexed by gn)
  h16* stackA;      // gm <  512 -> stackA[b][gm][offA + l]
  h16* stackB;      // gm >= 512 -> stackB[b][gm-512][offB + l]
  int lnShift;      // nodes-per-batch shift: 9 (d) or 7 (q)
  int offA, offB;
  __device__ void operator()(int, int gm, int gn, float v) const {
    const int b = gn >> lnShift, l = gn & ((1 << lnShift) - 1);
    const h16 sv = (h16)(w[gn] * v);
    if (gm < 512)
      stackA[((size_t)b * 512 + gm) * 640 + offA + l] = sv;
    else
      stackB[((size_t)b * 512 + (gm - 512)) * 640 + offB + l] = sv;
  }
};
// Agg GEMM: A = [mask'|node], Bt = [stackT|W_self], C[i][c] = self + msg/nb.
struct EpiAgg {
  const float* bias;  // b_self[c]
  float* out;         // fp32 final output or nullptr
  h16* nodeNext;      // next-iteration node buffer [i][c]
  int rowsPerB;       // 512 (d) or 128 (q)
  __device__ void operator()(int b, int gm, int gn, float v) const {
    const size_t row = (size_t)b * rowsPerB + gm;
    const float val = fmaxf(v + bias[gn], 0.f);
    if (out) out[row * 512 + gn] = val;
    nodeNext[row * 512 + gn] = (h16)val;
  }
};

// ---------------------------------------------------------------------------
// Combined dense launch: 2560 blocks. g = x*320 + yy; x = M-tile (0..7),
// yy<256 -> d-job (tileN=yy*128 into dnode), else q-job (yy-256).
// Same-yy blocks are 320 apart => same id%8 => same XCD (L2 reuse of B-tile).
// ---------------------------------------------------------------------------
__global__ __launch_bounds__(256, 3) void k_dense(Src saD, Src sbD, EpiDense epiD,
                                                  Src saQ, Src sbQ, EpiDense epiQ) {
  __shared__ __align__(16) h16 lds[2 * 2 * 4096];
  const int g = blockIdx.x;
  const int x = g / 320;
  const int yy = g % 320;
  if (yy < 256)
    gemm_body(0, (long)x * 128, (long)yy * 128, saD, sbD, 512, epiD, lds);
  else
    gemm_body(0, (long)x * 128, (long)(yy - 256) * 128, saQ, sbQ, 512, epiQ, lds);
}

// Combined agg launch: 1280 blocks. g = inner*64 + b; inner<16 -> d-job
// (x=inner>>2, y=inner&3), else q-job (x=0, y=inner-16).
// Same-batch blocks are 64 apart => same XCD (per-batch ~3MB ~ L2).
__global__ __launch_bounds__(256, 3) void k_agg(Src saD, Src sbD, EpiAgg epiD,
                                                Src saQ, Src sbQ, EpiAgg epiQ) {
  __shared__ __align__(16) h16 lds[2 * 2 * 4096];
  const int g = blockIdx.x;
  const int b = g & 63;
  const int inner = g >> 6;
  if (inner < 16)
    gemm_body(b, (long)(inner >> 2) * 128, (long)(inner & 3) * 128, saD, sbD, KAGG, epiD, lds);
  else
    gemm_body(b, 0L, (long)(inner - 16) * 128, saQ, sbQ, KAGG, epiQ, lds);
}

// --- small kernels ----------------------------------------------------------
__global__ __launch_bounds__(256) void k_convert(const float* __restrict__ dn,
                                                 const float* __restrict__ qn,
                                                 h16* __restrict__ dnb,
                                                 h16* __restrict__ qnb) {
  const size_t i4 = ((size_t)blockIdx.x * 256 + threadIdx.x) * 4;
  constexpr size_t TD = (size_t)MD * DIM;
  const float* src; h16* dst; size_t idx;
  if (i4 < TD) { src = dn; dst = dnb; idx = i4; }
  else         { src = qn; dst = qnb; idx = i4 - TD; }
  const float4 v = *(const float4*)&src[idx];
  h16x4 o; o.x = (h16)v.x; o.y = (h16)v.y; o.z = (h16)v.z; o.w = (h16)v.w;
  *(h16x4*)&dst[idx] = o;
}

__global__ __launch_bounds__(256) void k_wcat(const float* __restrict__ Wself,
                                              const float* __restrict__ Wdd,
                                              const float* __restrict__ Wqd,
                                              const float* __restrict__ Wqq,
                                              const float* __restrict__ Wdq,
                                              h16* __restrict__ catD,
                                              h16* __restrict__ catQ) {
  const int i = blockIdx.x * 256 + threadIdx.x;  // < 1536*512
  float vD, vQ;
  if (i < 512 * 512)       { vD = Wself[i];            vQ = vD; }
  else if (i < 1024 * 512) { vD = Wdd[i - 512 * 512];  vQ = Wqq[i - 512 * 512]; }
  else                     { vD = Wqd[i - 1024 * 512]; vQ = Wdq[i - 1024 * 512]; }
  catD[i] = (h16)vD; catQ[i] = (h16)vQ;
}

// maskD'[b][i][j] = graph/nb : j<512 dd, else dq (premultiplied by 1/max(nb,1))
__global__ __launch_bounds__(256) void k_maskD(const int* __restrict__ dd,
                                               const int* __restrict__ dq,
                                               h16* __restrict__ maskD) {
  const int row = blockIdx.x * 4 + (threadIdx.x >> 6);
  const int lane = threadIdx.x & 63;
  const int* pdd = dd + (size_t)row * 512;
  const int* pdq = dq + (size_t)row * 128;
  h16* pm = maskD + (size_t)row * 640;
  float vals[10];
  float s = 0.f;
#pragma unroll
  for (int t = 0; t < 10; t++) {
    const int j = lane + t * 64;
    const float v = (float)((j < 512) ? pdd[j] : pdq[j - 512]);
    vals[t] = v; s += v;
  }
  for (int m = 32; m; m >>= 1) s += __shfl_xor(s, m);
  const float inv = 1.f / fmaxf(s, 1.f);
#pragma unroll
  for (int t = 0; t < 10; t++) pm[lane + t * 64] = (h16)(vals[t] * inv);
}

__global__ __launch_bounds__(256) void k_maskQ(const int* __restrict__ qq,
                                               const int* __restrict__ qd,
                                               h16* __restrict__ maskQ) {
  const int row = blockIdx.x * 4 + (threadIdx.x >> 6);
  const int lane = threadIdx.x & 63;
  const int* pqq = qq + (size_t)row * 128;
  const int* pqd = qd + (size_t)row * 512;
  h16* pm = maskQ + (size_t)row * 640;
  float vals[10];
  float s = 0.f;
#pragma unroll
  for (int t = 0; t < 10; t++) {
    const int j = lane + t * 64;
    const float v = (float)((j < 128) ? pqq[j] : pqd[j - 128]);
    vals[t] = v; s += v;
  }
  for (int m = 32; m; m >>= 1) s += __shfl_xor(s, m);
  const float inv = 1.f / fmaxf(s, 1.f);
#pragma unroll
  for (int t = 0; t < 10; t++) pm[lane + t * 64] = (h16)(vals[t] * inv);
}

// sigmoid gate per node row: one wave per row (d rows then q rows)
__global__ __launch_bounds__(256) void k_w(const h16* __restrict__ dnb,
                                           const h16* __restrict__ qnb,
                                           const float* __restrict__ Wnw,
                                           const float* __restrict__ bnw,
                                           float* __restrict__ d_w,
                                           float* __restrict__ q_w,
                                           float* __restrict__ adw,
                                           float* __restrict__ aqw, int it) {
  const int row = blockIdx.x * 4 + (threadIdx.x >> 6);
  const int lane = threadIdx.x & 63;
  const bool isD = row < MD;
  const h16* node = isD ? dnb + (size_t)row * 512 : qnb + (size_t)(row - MD) * 512;
  const h16x8 v = *(const h16x8*)&node[lane * 8];
  const float4 w0 = *(const float4*)&Wnw[lane * 8];
  const float4 w1 = *(const float4*)&Wnw[lane * 8 + 4];
  float s = (float)v[0] * w0.x + (float)v[1] * w0.y + (float)v[2] * w0.z +
            (float)v[3] * w0.w + (float)v[4] * w1.x + (float)v[5] * w1.y +
            (float)v[6] * w1.z + (float)v[7] * w1.w;
  for (int m = 32; m; m >>= 1) s += __shfl_xor(s, m);
  if (lane == 0) {
    const float w = 1.f / (1.f + expf(-(s + bnw[0])));
    if (isD) {
      d_w[row] = w;
      adw[((size_t)(row >> 9) * STEPS + it) * 512 + (row & 511)] = w;
    } else {
      const int rq = row - MD;
      q_w[rq] = w;
      aqw[((size_t)(rq >> 7) * STEPS + it) * 128 + (rq & 127)] = w;
    }
  }
}

// ---------------------------------------------------------------------------
extern "C" void kernel_launch(void* const* d_in, const int* in_sizes, int n_in,
                              void* d_out, int out_size, void* d_ws, size_t ws_size,
                              hipStream_t stream) {
  (void)in_sizes; (void)n_in; (void)out_size; (void)ws_size;

  const float* d_node = (const float*)d_in[0];
  const float* q_node = (const float*)d_in[1];
  const int*   qq     = (const int*)d_in[2];
  const int*   dq     = (const int*)d_in[3];
  const int*   dd     = (const int*)d_in[4];
  const int*   qd     = (const int*)d_in[5];
  const float* W_nw   = (const float*)d_in[6];
  const float* b_nw   = (const float*)d_in[7];
  const float* W_self = (const float*)d_in[8];
  const float* b_self = (const float*)d_in[9];
  const float* W_dd   = (const float*)d_in[10];
  const float* W_qq   = (const float*)d_in[11];
  const float* W_dq   = (const float*)d_in[12];
  const float* W_qd   = (const float*)d_in[13];

  float* outd = (float*)d_out;                  // [B,Ld,D]
  float* outq = outd + (size_t)MD * DIM;        // [B,Lq,D]
  float* adw  = outq + (size_t)MQ * DIM;        // [B,STEPS,Ld]
  float* aqw  = adw + (size_t)B_ * STEPS * LD;  // [B,STEPS,Lq]

  char* p = (char*)d_ws;
  auto alloc = [&](size_t bytes) { char* r = p; p += (bytes + 255) & ~(size_t)255; return r; };
  h16* dnode[2], *qnode[2];
  dnode[0] = (h16*)alloc((size_t)MD * DIM * 2);
  dnode[1] = (h16*)alloc((size_t)MD * DIM * 2);
  qnode[0] = (h16*)alloc((size_t)MQ * DIM * 2);
  qnode[1] = (h16*)alloc((size_t)MQ * DIM * 2);
  h16* catD    = (h16*)alloc((size_t)1536 * 512 * 2);
  h16* catQ    = (h16*)alloc((size_t)1536 * 512 * 2);
  h16* maskD   = (h16*)alloc((size_t)B_ * LD * KST * 2);
  h16* maskQ   = (h16*)alloc((size_t)B_ * LQ * KST * 2);
  h16* stackDT = (h16*)alloc((size_t)B_ * 512 * KST * 2);
  h16* stackQT = (h16*)alloc((size_t)B_ * 512 * KST * 2);
  float* d_wb  = (float*)alloc((size_t)MD * 4);
  float* q_wb  = (float*)alloc((size_t)MQ * 4);

  // one-time prep
  k_convert<<<dim3((MD * DIM + MQ * DIM) / 4 / 256), 256, 0, stream>>>(d_node, q_node, dnode[0], qnode[0]);
  k_wcat<<<dim3(1536 * 512 / 256), 256, 0, stream>>>(W_self, W_dd, W_qd, W_qq, W_dq, catD, catQ);
  k_maskD<<<dim3(MD / 4), 256, 0, stream>>>(dd, dq, maskD);
  k_maskQ<<<dim3(MQ / 4), 256, 0, stream>>>(qq, qd, maskQ);

  for (int it = 0; it < STEPS; it++) {
    const bool last = (it == STEPS - 1);
    h16* ncur_d = dnode[it & 1];
    h16* nnext_d = dnode[(it & 1) ^ 1];
    h16* ncur_q = qnode[it & 1];
    h16* nnext_q = qnode[(it & 1) ^ 1];

    k_w<<<dim3((MD + MQ) / 4), 256, 0, stream>>>(ncur_d, ncur_q, W_nw, b_nw, d_wb, q_wb, adw, aqw, it);

    // combined dense: d-job A=catD[512:1536]=[W_dd|W_qd] Bt=dnode;
    //                 q-job A=catQ[512:1536]=[W_qq|W_dq] Bt=qnode
    {
      Src saD{catD + 512 * 512, 512, 0, catD + 512 * 512, 512, 0, 512};
      Src sbD{ncur_d, 512, 0, ncur_d, 512, 0, 512};
      Src saQ{catQ + 512 * 512, 512, 0, catQ + 512 * 512, 512, 0, 512};
      Src sbQ{ncur_q, 512, 0, ncur_q, 512, 0, 512};
      k_dense<<<dim3(2560), 256, 0, stream>>>(
          saD, sbD, EpiDense{d_wb, stackDT, stackQT, 9, 0, 128},
          saQ, sbQ, EpiDense{q_wb, stackQT, stackDT, 7, 0, 512});
    }
    // combined agg: d-job A=[maskD'|dnode] Bt=[stackDT|W_self];
    //               q-job A=[maskQ'|qnode] Bt=[stackQT|W_self]
    {
      Src saD{maskD, 640, (long)LD * KST, ncur_d, 512, (long)LD * DIM, KST};
      Src sbD{stackDT, 640, (long)512 * KST, catD, 512, 0, KST};
      Src saQ{maskQ, 640, (long)LQ * KST, ncur_q, 512, (long)LQ * DIM, KST};
      Src sbQ{stackQT, 640, (long)512 * KST, catQ, 512, 0, KST};
      k_agg<<<dim3(1280), 256, 0, stream>>>(
          saD, sbD, EpiAgg{b_self, last ? outd : nullptr, nnext_d, 512},
          saQ, sbQ, EpiAgg{b_self, last ? outq : nullptr, nnext_q, 128});
    }
  }
}

// Round 7
// 544.732 us; speedup vs baseline: 1.7553x; 1.0444x over previous
//
#include <hip/hip_runtime.h>
#include <cstdint>
#include <cstddef>

typedef _Float16 h16;
typedef __attribute__((ext_vector_type(8))) _Float16 h16x8;
typedef __attribute__((ext_vector_type(4))) _Float16 h16x4;
typedef __attribute__((ext_vector_type(4))) float f32x4;

constexpr int B_ = 64, LD = 512, LQ = 128, DIM = 512, STEPS = 2;
constexpr int MD = B_ * LD;   // 32768 d-rows total
constexpr int MQ = B_ * LQ;   // 8192 q-rows total
constexpr int KST = LD + LQ;  // 640 stacked-neighbor K
constexpr int KAGG = KST + DIM;  // 1152 = mask|node augmented K for agg GEMM

// async global->LDS, 16B per lane; LDS dest must be wave-uniform base + lane*16
#define ASYNC16(gp, lp)                                                          \
  __builtin_amdgcn_global_load_lds(                                              \
      (const __attribute__((address_space(1))) unsigned int*)(gp),               \
      (__attribute__((address_space(3))) unsigned int*)(lp), 16, 0, 0)

// A GEMM operand that switches source at k = ksplit (both K-contiguous).
struct Src {
  const h16* p0; int s0; long bstr0;  // rows for k in [0, ksplit)
  const h16* p1; int s1; long bstr1;  // rows for k in [ksplit, K)
  int ksplit;
};

// ---------------------------------------------------------------------------
// C = A * B^T tile kernel body. Block tile (WM*32) x 128, 4 waves as 2x2,
// each wave (WM*16) x 64 via WMx4 mfma_f32_16x16x32_f16 (fp32 accum).
// WM=8: 256x128 block tile — LDS traffic per MAC low enough that MFMA
// (1083 cyc/iter/block) exceeds LDS-pipe demand (~720 cyc) -> MFMA-bound.
// WM=4: 128x128 (for agg-q where M=128/batch).
// Double-buffered LDS staged by global_load_lds width=16; one __syncthreads
// per K-step drains the DMA for the tile consumed next.
// LDS swizzle (DMA-compatible, lane-linear dest): 16B chunk (row,kq) at
// chunk index row*4 + (kq ^ e(row)), e(row)=(row^(row>>2))&3. Staging thread
// t writes chunk t + 256*s; fragment ds_read_b128 covers all 8 bank-quads
// per 8-lane phase (conflict-free; r6 residual conflicts are DMA-intrinsic).
// MFMA 16x16x32 layouts (measured, m89/m91):
//   A-frag: m = lane&15, k = quad*8 + j ; B-frag: n = lane&15, k = quad*8+j
//   C/D:    col(n) = lane&15, row(m) = quad*4 + r
// ---------------------------------------------------------------------------
template <int WM, class Epi>
__device__ __forceinline__ void gemm_body(int b, long tileM, long tileN,
                                          Src sa, Src sb, int K,
                                          const Epi& epi, h16* lds) {
  constexpr int BM = WM * 32;        // block M: 256 or 128
  constexpr int AS = BM / 64;        // A staging segments: 4 or 2
  constexpr int AE = BM * 32;        // A elems per buffer
  constexpr int BUFE = AE + 4096;    // buffer stride in h16 elems

  const int tid = threadIdx.x;
  const int lane = tid & 63;
  const int wv = tid >> 6;
  const int wi = wv >> 1, wj = wv & 1;
  const int quad = lane >> 4, l16 = lane & 15;

  // staging mapping: thread t -> LDS chunk t (+256*s); global (row, kq)
  const int r = tid >> 2;                       // 0..63
  const int es = (r ^ (r >> 2)) & 3;
  const int kq = (tid & 3) ^ es;                // permuted k-quarter

  const h16* pa[2][AS];
  const h16* pb[2][2];
#pragma unroll
  for (int s = 0; s < AS; s++) {
    pa[0][s] = sa.p0 + (size_t)b * sa.bstr0 + (tileM + r + 64 * s) * (long)sa.s0 + kq * 8;
    pa[1][s] = sa.p1 + (size_t)b * sa.bstr1 + (tileM + r + 64 * s) * (long)sa.s1 + kq * 8 - sa.ksplit;
  }
#pragma unroll
  for (int s = 0; s < 2; s++) {
    pb[0][s] = sb.p0 + (size_t)b * sb.bstr0 + (tileN + r + 64 * s) * (long)sb.s0 + kq * 8;
    pb[1][s] = sb.p1 + (size_t)b * sb.bstr1 + (tileN + r + 64 * s) * (long)sb.s1 + kq * 8 - sb.ksplit;
  }

  // fragment LDS element offsets (buf 0); e depends only on l16
  const int ef = (l16 ^ (l16 >> 2)) & 3;
  int offA[WM], offB[4];
#pragma unroll
  for (int i = 0; i < WM; i++) {
    const int row = wi * WM * 16 + i * 16 + l16;
    offA[i] = (row * 4 + (quad ^ ef)) * 8;
  }
#pragma unroll
  for (int j = 0; j < 4; j++) {
    const int row = wj * 64 + j * 16 + l16;
    offB[j] = AE + (row * 4 + (quad ^ ef)) * 8;
  }

  f32x4 acc[WM][4] = {};
  const int T = K >> 5;  // even for all our shapes (16 or 36)

  auto dmaTile = [&](int t, int c) {
    const int k0 = t * 32;
    h16* base = lds + c * BUFE + tid * 8;
    const int sel = (k0 >= sa.ksplit);
#pragma unroll
    for (int s = 0; s < AS; s++) ASYNC16(pa[sel][s] + k0, base + s * 2048);
    const int selb = (k0 >= sb.ksplit);
#pragma unroll
    for (int s = 0; s < 2; s++) ASYNC16(pb[selb][s] + k0, base + AE + s * 2048);
  };
  auto mfmaStep = [&](int off) {
    h16x8 af[WM], bf[4];
#pragma unroll
    for (int i = 0; i < WM; i++) af[i] = *(const h16x8*)(lds + off + offA[i]);
#pragma unroll
    for (int j = 0; j < 4; j++) bf[j] = *(const h16x8*)(lds + off + offB[j]);
#pragma unroll
    for (int i = 0; i < WM; i++)
#pragma unroll
      for (int j = 0; j < 4; j++)
        acc[i][j] = __builtin_amdgcn_mfma_f32_16x16x32_f16(af[i], bf[j], acc[i][j], 0, 0, 0);
  };

  dmaTile(0, 0);  // prologue

  for (int t = 0; t < T; t += 2) {
    __syncthreads();                      // drains DMA(t -> buf0)
    dmaTile(t + 1, 1);                    // t+1 < T always (T even)
    mfmaStep(0);
    __syncthreads();                      // drains DMA(t+1 -> buf1)
    if (t + 2 < T) dmaTile(t + 2, 0);
    mfmaStep(BUFE);
  }

#pragma unroll
  for (int i = 0; i < WM; i++) {
#pragma unroll
    for (int j = 0; j < 4; j++) {
      const int gm0 = (int)tileM + wi * WM * 16 + i * 16 + quad * 4;
      const int gn  = (int)tileN + wj * 64 + j * 16 + l16;
#pragma unroll
      for (int rr = 0; rr < 4; rr++) epi(b, gm0 + rr, gn, acc[i][j][rr]);
    }
  }
}

// --- epilogues --------------------------------------------------------------
// Dense GEMM: A = [W_x|W_y] (1024 rows), Bt = node (all batches), C[o][node].
struct EpiDense {
  const float* w;   // gate per node (indexed by gn)
  h16* stackA;      // gm <  512 -> stackA[b][gm][offA + l]
  h16* stackB;      // gm >= 512 -> stackB[b][gm-512][offB + l]
  int lnShift;      // nodes-per-batch shift: 9 (d) or 7 (q)
  int offA, offB;
  __device__ void operator()(int, int gm, int gn, float v) const {
    const int b = gn >> lnShift, l = gn & ((1 << lnShift) - 1);
    const h16 sv = (h16)(w[gn] * v);
    if (gm < 512)
      stackA[((size_t)b * 512 + gm) * 640 + offA + l] = sv;
    else
      stackB[((size_t)b * 512 + (gm - 512)) * 640 + offB + l] = sv;
  }
};
// Agg GEMM: A = [mask'|node], Bt = [stackT|W_self], C[i][c] = self + msg/nb.
struct EpiAgg {
  const float* bias;  // b_self[c]
  float* out;         // fp32 final output or nullptr
  h16* nodeNext;      // next-iteration node buffer [i][c]
  int rowsPerB;       // 512 (d) or 128 (q)
  __device__ void operator()(int b, int gm, int gn, float v) const {
    const size_t row = (size_t)b * rowsPerB + gm;
    const float val = fmaxf(v + bias[gn], 0.f);
    if (out) out[row * 512 + gn] = val;
    nodeNext[row * 512 + gn] = (h16)val;
  }
};

// ---------------------------------------------------------------------------
// Combined dense launch: 1280 blocks. g = x*320 + yy; x = M-tile of 256
// (0..3), yy<256 -> d-job (tileN=yy*128), else q-job (yy-256). Same-yy blocks
// are 320 apart => same XCD (L2 reuse of the shared node B-tile).
// ---------------------------------------------------------------------------
__global__ __launch_bounds__(256, 2) void k_dense(Src saD, Src sbD, EpiDense epiD,
                                                  Src saQ, Src sbQ, EpiDense epiQ) {
  __shared__ __align__(16) h16 lds[2 * (256 * 32 + 128 * 32)];  // 48 KB
  const int g = blockIdx.x;
  const int x = g / 320;
  const int yy = g % 320;
  if (yy < 256)
    gemm_body<8>(0, (long)x * 256, (long)yy * 128, saD, sbD, 512, epiD, lds);
  else
    gemm_body<8>(0, (long)x * 256, (long)(yy - 256) * 128, saQ, sbQ, 512, epiQ, lds);
}

// Combined agg launch: 768 blocks. g = inner*64 + b; inner<8 -> d-job Big
// (x=inner>>2 of 256 rows, y=inner&3), else q-job Small (y=inner-8).
// Same-batch blocks are 64 apart => same XCD (per-batch working set ~3MB).
__global__ __launch_bounds__(256, 2) void k_agg(Src saD, Src sbD, EpiAgg epiD,
                                                Src saQ, Src sbQ, EpiAgg epiQ) {
  __shared__ __align__(16) h16 lds[2 * (256 * 32 + 128 * 32)];  // 48 KB
  const int g = blockIdx.x;
  const int b = g & 63;
  const int inner = g >> 6;
  if (inner < 8)
    gemm_body<8>(b, (long)(inner >> 2) * 256, (long)(inner & 3) * 128, saD, sbD, KAGG, epiD, lds);
  else
    gemm_body<4>(b, 0L, (long)(inner - 8) * 128, saQ, sbQ, KAGG, epiQ, lds);
}

// --- small kernels ----------------------------------------------------------
__global__ __launch_bounds__(256) void k_convert(const float* __restrict__ dn,
                                                 const float* __restrict__ qn,
                                                 h16* __restrict__ dnb,
                                                 h16* __restrict__ qnb) {
  const size_t i4 = ((size_t)blockIdx.x * 256 + threadIdx.x) * 4;
  constexpr size_t TD = (size_t)MD * DIM;
  const float* src; h16* dst; size_t idx;
  if (i4 < TD) { src = dn; dst = dnb; idx = i4; }
  else         { src = qn; dst = qnb; idx = i4 - TD; }
  const float4 v = *(const float4*)&src[idx];
  h16x4 o; o.x = (h16)v.x; o.y = (h16)v.y; o.z = (h16)v.z; o.w = (h16)v.w;
  *(h16x4*)&dst[idx] = o;
}

__global__ __launch_bounds__(256) void k_wcat(const float* __restrict__ Wself,
                                              const float* __restrict__ Wdd,
                                              const float* __restrict__ Wqd,
                                              const float* __restrict__ Wqq,
                                              const float* __restrict__ Wdq,
                                              h16* __restrict__ catD,
                                              h16* __restrict__ catQ) {
  const int i = blockIdx.x * 256 + threadIdx.x;  // < 1536*512
  float vD, vQ;
  if (i < 512 * 512)       { vD = Wself[i];            vQ = vD; }
  else if (i < 1024 * 512) { vD = Wdd[i - 512 * 512];  vQ = Wqq[i - 512 * 512]; }
  else                     { vD = Wqd[i - 1024 * 512]; vQ = Wdq[i - 1024 * 512]; }
  catD[i] = (h16)vD; catQ[i] = (h16)vQ;
}

// maskD'[b][i][j] = graph/nb : j<512 dd, else dq (premultiplied by 1/max(nb,1))
__global__ __launch_bounds__(256) void k_maskD(const int* __restrict__ dd,
                                               const int* __restrict__ dq,
                                               h16* __restrict__ maskD) {
  const int row = blockIdx.x * 4 + (threadIdx.x >> 6);
  const int lane = threadIdx.x & 63;
  const int* pdd = dd + (size_t)row * 512;
  const int* pdq = dq + (size_t)row * 128;
  h16* pm = maskD + (size_t)row * 640;
  float vals[10];
  float s = 0.f;
#pragma unroll
  for (int t = 0; t < 10; t++) {
    const int j = lane + t * 64;
    const float v = (float)((j < 512) ? pdd[j] : pdq[j - 512]);
    vals[t] = v; s += v;
  }
  for (int m = 32; m; m >>= 1) s += __shfl_xor(s, m);
  const float inv = 1.f / fmaxf(s, 1.f);
#pragma unroll
  for (int t = 0; t < 10; t++) pm[lane + t * 64] = (h16)(vals[t] * inv);
}

__global__ __launch_bounds__(256) void k_maskQ(const int* __restrict__ qq,
                                               const int* __restrict__ qd,
                                               h16* __restrict__ maskQ) {
  const int row = blockIdx.x * 4 + (threadIdx.x >> 6);
  const int lane = threadIdx.x & 63;
  const int* pqq = qq + (size_t)row * 128;
  const int* pqd = qd + (size_t)row * 512;
  h16* pm = maskQ + (size_t)row * 640;
  float vals[10];
  float s = 0.f;
#pragma unroll
  for (int t = 0; t < 10; t++) {
    const int j = lane + t * 64;
    const float v = (float)((j < 128) ? pqq[j] : pqd[j - 128]);
    vals[t] = v; s += v;
  }
  for (int m = 32; m; m >>= 1) s += __shfl_xor(s, m);
  const float inv = 1.f / fmaxf(s, 1.f);
#pragma unroll
  for (int t = 0; t < 10; t++) pm[lane + t * 64] = (h16)(vals[t] * inv);
}

// sigmoid gate per node row: one wave per row (d rows then q rows)
__global__ __launch_bounds__(256) void k_w(const h16* __restrict__ dnb,
                                           const h16* __restrict__ qnb,
                                           const float* __restrict__ Wnw,
                                           const float* __restrict__ bnw,
                                           float* __restrict__ d_w,
                                           float* __restrict__ q_w,
                                           float* __restrict__ adw,
                                           float* __restrict__ aqw, int it) {
  const int row = blockIdx.x * 4 + (threadIdx.x >> 6);
  const int lane = threadIdx.x & 63;
  const bool isD = row < MD;
  const h16* node = isD ? dnb + (size_t)row * 512 : qnb + (size_t)(row - MD) * 512;
  const h16x8 v = *(const h16x8*)&node[lane * 8];
  const float4 w0 = *(const float4*)&Wnw[lane * 8];
  const float4 w1 = *(const float4*)&Wnw[lane * 8 + 4];
  float s = (float)v[0] * w0.x + (float)v[1] * w0.y + (float)v[2] * w0.z +
            (float)v[3] * w0.w + (float)v[4] * w1.x + (float)v[5] * w1.y +
            (float)v[6] * w1.z + (float)v[7] * w1.w;
  for (int m = 32; m; m >>= 1) s += __shfl_xor(s, m);
  if (lane == 0) {
    const float w = 1.f / (1.f + expf(-(s + bnw[0])));
    if (isD) {
      d_w[row] = w;
      adw[((size_t)(row >> 9) * STEPS + it) * 512 + (row & 511)] = w;
    } else {
      const int rq = row - MD;
      q_w[rq] = w;
      aqw[((size_t)(rq >> 7) * STEPS + it) * 128 + (rq & 127)] = w;
    }
  }
}

// ---------------------------------------------------------------------------
extern "C" void kernel_launch(void* const* d_in, const int* in_sizes, int n_in,
                              void* d_out, int out_size, void* d_ws, size_t ws_size,
                              hipStream_t stream) {
  (void)in_sizes; (void)n_in; (void)out_size; (void)ws_size;

  const float* d_node = (const float*)d_in[0];
  const float* q_node = (const float*)d_in[1];
  const int*   qq     = (const int*)d_in[2];
  const int*   dq     = (const int*)d_in[3];
  const int*   dd     = (const int*)d_in[4];
  const int*   qd     = (const int*)d_in[5];
  const float* W_nw   = (const float*)d_in[6];
  const float* b_nw   = (const float*)d_in[7];
  const float* W_self = (const float*)d_in[8];
  const float* b_self = (const float*)d_in[9];
  const float* W_dd   = (const float*)d_in[10];
  const float* W_qq   = (const float*)d_in[11];
  const float* W_dq   = (const float*)d_in[12];
  const float* W_qd   = (const float*)d_in[13];

  float* outd = (float*)d_out;                  // [B,Ld,D]
  float* outq = outd + (size_t)MD * DIM;        // [B,Lq,D]
  float* adw  = outq + (size_t)MQ * DIM;        // [B,STEPS,Ld]
  float* aqw  = adw + (size_t)B_ * STEPS * LD;  // [B,STEPS,Lq]

  char* p = (char*)d_ws;
  auto alloc = [&](size_t bytes) { char* r = p; p += (bytes + 255) & ~(size_t)255; return r; };
  h16* dnode[2], *qnode[2];
  dnode[0] = (h16*)alloc((size_t)MD * DIM * 2);
  dnode[1] = (h16*)alloc((size_t)MD * DIM * 2);
  qnode[0] = (h16*)alloc((size_t)MQ * DIM * 2);
  qnode[1] = (h16*)alloc((size_t)MQ * DIM * 2);
  h16* catD    = (h16*)alloc((size_t)1536 * 512 * 2);
  h16* catQ    = (h16*)alloc((size_t)1536 * 512 * 2);
  h16* maskD   = (h16*)alloc((size_t)B_ * LD * KST * 2);
  h16* maskQ   = (h16*)alloc((size_t)B_ * LQ * KST * 2);
  h16* stackDT = (h16*)alloc((size_t)B_ * 512 * KST * 2);
  h16* stackQT = (h16*)alloc((size_t)B_ * 512 * KST * 2);
  float* d_wb  = (float*)alloc((size_t)MD * 4);
  float* q_wb  = (float*)alloc((size_t)MQ * 4);

  // one-time prep
  k_convert<<<dim3((MD * DIM + MQ * DIM) / 4 / 256), 256, 0, stream>>>(d_node, q_node, dnode[0], qnode[0]);
  k_wcat<<<dim3(1536 * 512 / 256), 256, 0, stream>>>(W_self, W_dd, W_qd, W_qq, W_dq, catD, catQ);
  k_maskD<<<dim3(MD / 4), 256, 0, stream>>>(dd, dq, maskD);
  k_maskQ<<<dim3(MQ / 4), 256, 0, stream>>>(qq, qd, maskQ);

  for (int it = 0; it < STEPS; it++) {
    const bool last = (it == STEPS - 1);
    h16* ncur_d = dnode[it & 1];
    h16* nnext_d = dnode[(it & 1) ^ 1];
    h16* ncur_q = qnode[it & 1];
    h16* nnext_q = qnode[(it & 1) ^ 1];

    k_w<<<dim3((MD + MQ) / 4), 256, 0, stream>>>(ncur_d, ncur_q, W_nw, b_nw, d_wb, q_wb, adw, aqw, it);

    // combined dense: d-job A=catD[512:1536]=[W_dd|W_qd] Bt=dnode;
    //                 q-job A=catQ[512:1536]=[W_qq|W_dq] Bt=qnode
    {
      Src saD{catD + 512 * 512, 512, 0, catD + 512 * 512, 512, 0, 512};
      Src sbD{ncur_d, 512, 0, ncur_d, 512, 0, 512};
      Src saQ{catQ + 512 * 512, 512, 0, catQ + 512 * 512, 512, 0, 512};
      Src sbQ{ncur_q, 512, 0, ncur_q, 512, 0, 512};
      k_dense<<<dim3(1280), 256, 0, stream>>>(
          saD, sbD, EpiDense{d_wb, stackDT, stackQT, 9, 0, 128},
          saQ, sbQ, EpiDense{q_wb, stackQT, stackDT, 7, 0, 512});
    }
    // combined agg: d-job A=[maskD'|dnode] Bt=[stackDT|W_self];
    //               q-job A=[maskQ'|qnode] Bt=[stackQT|W_self]
    {
      Src saD{maskD, 640, (long)LD * KST, ncur_d, 512, (long)LD * DIM, KST};
      Src sbD{stackDT, 640, (long)512 * KST, catD, 512, 0, KST};
      Src saQ{maskQ, 640, (long)LQ * KST, ncur_q, 512, (long)LQ * DIM, KST};
      Src sbQ{stackQT, 640, (long)512 * KST, catQ, 512, 0, KST};
      k_agg<<<dim3(768), 256, 0, stream>>>(
          saD, sbD, EpiAgg{b_self, last ? outd : nullptr, nnext_d, 512},
          saQ, sbQ, EpiAgg{b_self, last ? outq : nullptr, nnext_q, 128});
    }
  }
}